// Round 15
// baseline (610.638 us; speedup 1.0000x reference)
//
#include <hip/hip_runtime.h>
#include <hip/hip_bf16.h>

// Problem dims (fixed by reference)
#define PD 128   // packets
#define BD 32    // batch
#define SD 64    // bytes per packet (byte-GRU seq len)
#define ED 50    // embedding size
#define HD 128   // hidden (byte and packet)
#define GD 384   // 3*H gates
#define ND 4096  // P*B byte-level batch
#define VD 65536 // vocab
#define LW 128   // LDS row stride in u16 (measured optimum: r7 ladder)

typedef __attribute__((ext_vector_type(8))) short bf16x8;
typedef __attribute__((ext_vector_type(4))) float f32x4;

__device__ __forceinline__ float sigm(float x) { return 1.0f / (1.0f + __expf(-x)); }
__device__ __forceinline__ float tanh_f(float x) { return 1.0f - 2.0f / (__expf(2.0f * x) + 1.0f); }

__device__ __forceinline__ unsigned short f2b(float f) {  // f32 -> bf16 raw, RNE
    union { float f; unsigned u; } a; a.f = f;
    unsigned r = a.u + 0x7FFFu + ((a.u >> 16) & 1u);
    return (unsigned short)(r >> 16);
}
__device__ __forceinline__ float b2f(unsigned short h) {
    union { unsigned u; float f; } a; a.u = ((unsigned)h) << 16; return a.f;
}

union frag_u { bf16x8 v; unsigned short s[8]; };

__device__ __forceinline__ void pin_v(bf16x8& v) { asm volatile("" : "+v"(v)); }

#define MFMA(acc, a, b) acc = __builtin_amdgcn_mfma_f32_16x16x32_bf16(a, b, acc, 0, 0, 0)

// Raw LDS-only barrier: does NOT drain vmcnt (global stores stay in flight).
__device__ __forceinline__ void block_sync_lds() {
    asm volatile("s_waitcnt lgkmcnt(0)" ::: "memory");
    __builtin_amdgcn_sched_barrier(0);
    __builtin_amdgcn_s_barrier();
    __builtin_amdgcn_sched_barrier(0);
}

// ---------------------------------------------------------------------------
// Prep: emb pad+convert; TRANSPOSED weights for coalesced reads.
//   aWT [c][e] (256x64), pWT [d][e][g] (2x64x384), paWT [c][h] (256x128)
// ---------------------------------------------------------------------------
__global__ void prep_all(const float* __restrict__ emb, unsigned short* __restrict__ embHi,
                         const float* __restrict__ aW, float* __restrict__ aWT,
                         const float* __restrict__ pWih, float* __restrict__ pWT,
                         const float* __restrict__ paW, float* __restrict__ paWT) {
    int idx = blockIdx.x * 256 + threadIdx.x;
    if (idx < VD * 64) {
        int row = idx >> 6, e = idx & 63;
        float v = (e < ED) ? emb[row * ED + e] : 0.f;
        embHi[idx] = f2b(v);
    }
    if (idx < 256 * 64) {
        int c = idx >> 6, e = idx & 63;
        aWT[idx] = (e < ED) ? aW[e * 256 + c] : 0.f;
    }
    if (idx < 2 * 64 * GD) {
        int g = idx % GD, r = idx / GD;   // r = d*64+e
        int d = r >> 6, e = r & 63;
        pWT[idx] = (e < ED) ? pWih[((size_t)(d * GD + g)) * ED + e] : 0.f;
    }
    if (idx < 256 * HD) {                 // paWT[c*128+h]
        int c = idx >> 7, h = idx & 127;
        paWT[idx] = paW[h * 256 + c];
    }
}

// ---------------------------------------------------------------------------
// K1: byte-level bi-GRU via MFMA, split-bf16 precision compensation.
// (r11/r13 structure exactly: plateau config, best measured.)
// ---------------------------------------------------------------------------
__global__ __attribute__((amdgpu_flat_work_group_size(512, 512), amdgpu_waves_per_eu(2, 2)))
void byte_gru_mfma(
    const int* __restrict__ flow, const unsigned short* __restrict__ embHi,
    const float* __restrict__ Wih, const float* __restrict__ Whh,
    const float* __restrict__ h0b,
    unsigned short* __restrict__ y, float* __restrict__ hn) {
    const int dir   = blockIdx.x >> 7;
    const int chunk = blockIdx.x & 127;
    const int n0    = chunk * 32;
    const int tid   = threadIdx.x;
    const int w     = tid >> 6;
    const int lane  = tid & 63;
    const int col   = lane & 15;
    const int kq    = lane >> 4;
    const int u     = w * 16 + col;

    __shared__ unsigned short HHI[2][32 * LW];
    __shared__ unsigned short HLO[2][32 * LW];
    __shared__ int FLOWT[SD * 32];

    const int yrow = tid >> 4;
    const int yu0  = (tid & 15) * 8;
    const int ysw  = yrow * LW + (yu0 ^ ((yrow & 7) << 3));

    bf16x8 WHh[3][4], WHl[3][4], WXh[3][2], WXl[3][2];
    {
        const float* WhhD = Whh + dir * GD * HD;
        #pragma unroll
        for (int g3 = 0; g3 < 3; ++g3) {
            const float* row = WhhD + (g3 * HD + u) * HD;
            #pragma unroll
            for (int kt = 0; kt < 4; ++kt) {
                const int k0 = kt * 32 + kq * 8;
                frag_u h_, l_;
                #pragma unroll
                for (int b = 0; b < 8; ++b) {
                    float v = row[k0 + b];
                    unsigned short hi = f2b(v);
                    h_.s[b] = hi; l_.s[b] = f2b(v - b2f(hi));
                }
                WHh[g3][kt] = h_.v; WHl[g3][kt] = l_.v;
                pin_v(WHh[g3][kt]); pin_v(WHl[g3][kt]);
            }
        }
        const float* WihD = Wih + dir * GD * ED;
        #pragma unroll
        for (int g3 = 0; g3 < 3; ++g3) {
            const float* row = WihD + (g3 * HD + u) * ED;
            #pragma unroll
            for (int kx = 0; kx < 2; ++kx) {
                const int k0 = kx * 32 + kq * 8;
                frag_u h_, l_;
                #pragma unroll
                for (int b = 0; b < 8; ++b) {
                    const int e = k0 + b;
                    float v = (e < ED) ? row[e] : 0.f;
                    unsigned short hi = f2b(v);
                    h_.s[b] = hi; l_.s[b] = f2b(v - b2f(hi));
                }
                WXh[g3][kx] = h_.v; WXl[g3][kx] = l_.v;
                pin_v(WXh[g3][kx]); pin_v(WXl[g3][kx]);
            }
        }
    }

    float hreg[2][4];
    {
        const float* h0row = h0b + (size_t)((chunk * 2 + dir) * 32) * HD;
        #pragma unroll
        for (int m = 0; m < 2; ++m)
            #pragma unroll
            for (int j = 0; j < 4; ++j)
                hreg[m][j] = h0row[(m * 16 + kq * 4 + j) * HD + u];
        for (int idx = tid; idx < 32 * HD; idx += 512) {
            int seq = idx >> 7, uu = idx & 127;
            float v = h0row[idx];
            unsigned short hi = f2b(v);
            int sw = seq * LW + (uu ^ ((seq & 7) << 3));
            HHI[0][sw] = hi; HLO[0][sw] = f2b(v - b2f(hi));
        }
        for (int j = tid; j < SD * 32; j += 512) {
            int s = j >> 5, seq = j & 31;
            FLOWT[j] = flow[(n0 + seq) * SD + s];
        }
    }
    block_sync_lds();

    bf16x8 xa00, xa01, xa10, xa11;
    {
        const int s0 = dir ? (SD - 1) : 0;
        int i0 = FLOWT[s0 * 32 + col];
        int i1 = FLOWT[s0 * 32 + 16 + col];
        const bf16x8* r0 = (const bf16x8*)(embHi + (size_t)i0 * 64);
        const bf16x8* r1 = (const bf16x8*)(embHi + (size_t)i1 * 64);
        xa00 = r0[kq]; xa01 = r0[4 + kq];
        xa10 = r1[kq]; xa11 = r1[4 + kq];
    }

    int par = 0;
    for (int t = 0; t < SD; ++t) {
        const int s = dir ? (SD - 1 - t) : t;

        if (t > 0) {
            const int sp = dir ? (SD - t) : (t - 1);
            uint4 v = *(const uint4*)&HHI[par][ysw];
            *(uint4*)&y[((size_t)(sp * ND) + n0 + yrow) * 256 + dir * HD + yu0] = v;
        }

        bf16x8 xn00, xn01, xn10, xn11;
        if (t < SD - 1) {
            const int sn = dir ? (SD - 2 - t) : (t + 1);
            int i0 = FLOWT[sn * 32 + col];
            int i1 = FLOWT[sn * 32 + 16 + col];
            const bf16x8* r0 = (const bf16x8*)(embHi + (size_t)i0 * 64);
            const bf16x8* r1 = (const bf16x8*)(embHi + (size_t)i1 * 64);
            xn00 = r0[kq]; xn01 = r0[4 + kq];
            xn10 = r1[kq]; xn11 = r1[4 + kq];
        }

        f32x4 aR[2], aZ[2], aHN[2], aXN[2];
        const f32x4 zero = {0.f, 0.f, 0.f, 0.f};
        #pragma unroll
        for (int m = 0; m < 2; ++m) { aR[m] = zero; aZ[m] = zero; aHN[m] = zero; aXN[m] = zero; }

        const unsigned short* HHIp = HHI[par];
        const unsigned short* HLOp = HLO[par];
        #pragma unroll
        for (int kt = 0; kt < 4; ++kt) {
            const int off = kt * 32 + kq * 8;
            const int sw0 = col * LW + (off ^ ((col & 7) << 3));
            const int sw1 = sw0 + 16 * LW;
            bf16x8 ah0 = *(const bf16x8*)&HHIp[sw0];
            bf16x8 al0 = *(const bf16x8*)&HLOp[sw0];
            bf16x8 ah1 = *(const bf16x8*)&HHIp[sw1];
            bf16x8 al1 = *(const bf16x8*)&HLOp[sw1];
            MFMA(aR[0], ah0, WHh[0][kt]); MFMA(aR[0], al0, WHh[0][kt]); MFMA(aR[0], ah0, WHl[0][kt]);
            MFMA(aZ[0], ah0, WHh[1][kt]); MFMA(aZ[0], al0, WHh[1][kt]); MFMA(aZ[0], ah0, WHl[1][kt]);
            MFMA(aHN[0], ah0, WHh[2][kt]); MFMA(aHN[0], al0, WHh[2][kt]); MFMA(aHN[0], ah0, WHl[2][kt]);
            MFMA(aR[1], ah1, WHh[0][kt]); MFMA(aR[1], al1, WHh[0][kt]); MFMA(aR[1], ah1, WHl[0][kt]);
            MFMA(aZ[1], ah1, WHh[1][kt]); MFMA(aZ[1], al1, WHh[1][kt]); MFMA(aZ[1], ah1, WHl[1][kt]);
            MFMA(aHN[1], ah1, WHh[2][kt]); MFMA(aHN[1], al1, WHh[2][kt]); MFMA(aHN[1], ah1, WHl[2][kt]);
        }
        #pragma unroll
        for (int kx = 0; kx < 2; ++kx) {
            bf16x8 x0 = kx ? xa01 : xa00;
            bf16x8 x1 = kx ? xa11 : xa10;
            MFMA(aR[0], x0, WXh[0][kx]); MFMA(aR[0], x0, WXl[0][kx]);
            MFMA(aZ[0], x0, WXh[1][kx]); MFMA(aZ[0], x0, WXl[1][kx]);
            MFMA(aXN[0], x0, WXh[2][kx]); MFMA(aXN[0], x0, WXl[2][kx]);
            MFMA(aR[1], x1, WXh[0][kx]); MFMA(aR[1], x1, WXl[0][kx]);
            MFMA(aZ[1], x1, WXh[1][kx]); MFMA(aZ[1], x1, WXl[1][kx]);
            MFMA(aXN[1], x1, WXh[2][kx]); MFMA(aXN[1], x1, WXl[2][kx]);
        }

        unsigned short* HHIn = HHI[par ^ 1];
        unsigned short* HLOn = HLO[par ^ 1];
        #pragma unroll
        for (int m = 0; m < 2; ++m)
            #pragma unroll
            for (int j = 0; j < 4; ++j) {
                float r = sigm(aR[m][j]);
                float z = sigm(aZ[m][j]);
                float nn = tanh_f(aXN[m][j] + r * aHN[m][j]);
                float hnew = (1.f - z) * nn + z * hreg[m][j];
                hreg[m][j] = hnew;
                __hip_bfloat16 bh = __float2bfloat16(hnew);
                unsigned short hi = *(unsigned short*)&bh;
                __hip_bfloat16 bl = __float2bfloat16(hnew - b2f(hi));
                const int seq = m * 16 + kq * 4 + j;
                const int sw = seq * LW + (u ^ ((seq & 7) << 3));
                HHIn[sw] = hi;
                HLOn[sw] = *(unsigned short*)&bl;
            }
        block_sync_lds();
        xa00 = xn00; xa01 = xn01; xa10 = xn10; xa11 = xn11;
        par ^= 1;
    }
    {
        const int sl = dir ? 0 : (SD - 1);
        uint4 v = *(const uint4*)&HHI[par][ysw];
        *(uint4*)&y[((size_t)(sl * ND) + n0 + yrow) * 256 + dir * HD + yu0] = v;
    }
    #pragma unroll
    for (int m = 0; m < 2; ++m)
        #pragma unroll
        for (int j = 0; j < 4; ++j) {
            int seq = m * 16 + kq * 4 + j;
            hn[((size_t)dir * ND + n0 + seq) * HD + u] = hreg[m][j];
        }
}

// ---------------------------------------------------------------------------
// K2: byte attention -> ctx only. v15: enc/pxw hoisted to enc_pxw (they were
// re-reading 260KB of weights per block x 4096 blocks = ~1GB of L2 traffic).
// ---------------------------------------------------------------------------
__global__ __launch_bounds__(256) void byte_attn(
    const unsigned short* __restrict__ y, const float* __restrict__ hn,
    float* __restrict__ ctxg) {
    const int n = blockIdx.x;
    const int p = n >> 5, irow = n & 31;
    const int tid = threadIdx.x;
    __shared__ unsigned short yl[SD][256];
    __shared__ float hnl[256];
    __shared__ float red[256];
    __shared__ float red2[256];
    __shared__ float awl[SD];

    for (int idx = tid; idx < SD * 32; idx += 256) {
        int s = idx >> 5, cc = (idx & 31) * 8;
        *(uint4*)&yl[s][cc] = *(const uint4*)&y[((s * ND) + n) * 256 + cc];
    }
    {   // hn_p reshape quirk: flat idx = irow*256+c over (2,32,128)
        int c = tid;
        int idx = irow * 256 + c;
        int d = idx >> 12, bb = (idx >> 7) & 31, uu = idx & 127;
        hnl[c] = hn[(d * ND + p * 32 + bb) * HD + uu];
    }
    __syncthreads();
    {   // scores: 2-wide, skewed to spread banks
        int s = tid & 63, grp = tid >> 6;
        float acc = 0.f;
        for (int k = 0; k < 32; ++k) {
            int c2 = grp * 32 + ((s + k) & 31);
            unsigned pair = *(const unsigned*)&yl[s][c2 * 2];
            float2 hv = *(const float2*)&hnl[c2 * 2];
            union { unsigned u; float f; } lo, hi;
            lo.u = pair << 16; hi.u = pair & 0xFFFF0000u;
            acc += lo.f * hv.x + hi.f * hv.y;
        }
        red[grp * 64 + s] = acc;
    }
    __syncthreads();
    if (tid < 64) {
        float sc = red[tid] + red[64 + tid] + red[128 + tid] + red[192 + tid];
        float m = sc;
        #pragma unroll
        for (int o = 32; o; o >>= 1) m = fmaxf(m, __shfl_xor(m, o));
        float e = __expf(sc - m);
        float ssum = e;
        #pragma unroll
        for (int o = 32; o; o >>= 1) ssum += __shfl_xor(ssum, o);
        awl[tid] = e / ssum;
    }
    __syncthreads();
    {   // ctx: thread = (column-pair c2, s-half sh); 32 x ds_read_b32 each
        int c2 = tid & 127, sh = tid >> 7;
        float a0 = 0.f, a1 = 0.f;
        const int s0 = sh * 32;
        for (int s = s0; s < s0 + 32; ++s) {
            unsigned pair = *(const unsigned*)&yl[s][c2 * 2];
            union { unsigned u; float f; } lo, hi;
            lo.u = pair << 16; hi.u = pair & 0xFFFF0000u;
            float aw = awl[s];
            a0 += aw * lo.f; a1 += aw * hi.f;
        }
        float* dst = sh ? red2 : red;
        *(float2*)&dst[c2 * 2] = make_float2(a0, a1);
    }
    __syncthreads();
    ctxg[(size_t)n * 256 + tid] = red[tid] + red2[tid];   // coalesced 1KB
}

// ---------------------------------------------------------------------------
// K2.5: enc + pkt-GRU input projection, tiled for weight reuse.
// Block = packet p (128 blocks x 768 threads): ctx tile staged once; pWT
// read ONCE per block (32x reuse); aWT amortized 8 rows per thread.
// ---------------------------------------------------------------------------
__global__ __launch_bounds__(768) void enc_pxw(
    const float* __restrict__ ctxg, const float* __restrict__ aWT,
    const float* __restrict__ ab, const float* __restrict__ pWT,
    float* __restrict__ pxw) {
    const int p = blockIdx.x;
    const int tid = threadIdx.x;   // 0..767
    __shared__ float ctxl[32][257];
    __shared__ float encl[32][52];

    for (int idx = tid; idx < 32 * 256; idx += 768) {
        int r = idx >> 8, c = idx & 255;
        ctxl[r][c] = ctxg[(size_t)(p * 32 + r) * 256 + c];
    }
    __syncthreads();
    // enc: threads 0..511 = (e 0..63, rg 0..7); 4 rows each; coalesced aWT
    if (tid < 512) {
        int e = tid & 63, rg = tid >> 6;
        float a0 = 0.f, a1 = 0.f, a2 = 0.f, a3 = 0.f;
        for (int c = 0; c < 256; ++c) {
            float wv = aWT[c * 64 + e];
            a0 += ctxl[rg * 4 + 0][c] * wv;
            a1 += ctxl[rg * 4 + 1][c] * wv;
            a2 += ctxl[rg * 4 + 2][c] * wv;
            a3 += ctxl[rg * 4 + 3][c] * wv;
        }
        if (e < ED) {
            float bb = ab[e];
            encl[rg * 4 + 0][e] = a0 + bb;
            encl[rg * 4 + 1][e] = a1 + bb;
            encl[rg * 4 + 2][e] = a2 + bb;
            encl[rg * 4 + 3][e] = a3 + bb;
        }
    }
    __syncthreads();
    // pxw: thread = flat gate fg (0..767); weights register-resident, 32x reuse
    {
        int d = tid >= GD, g = tid - d * GD;
        float wreg[ED];
        #pragma unroll 2
        for (int e = 0; e < ED; ++e) wreg[e] = pWT[((size_t)(d * 64 + e)) * GD + g];
        for (int irow = 0; irow < 32; ++irow) {
            float acc = 0.f;
            #pragma unroll 2
            for (int e = 0; e < ED; ++e) acc += encl[irow][e] * wreg[e];  // broadcast reads
            pxw[((size_t)(d * PD + p) * 32 + irow) * GD + g] = acc;
        }
    }
}

// ---------------------------------------------------------------------------
// K3: packet-level bi-GRU. (r13 split-K structure: best measured.)
// ---------------------------------------------------------------------------
__global__ __launch_bounds__(768, 1) void pkt_gru(
    const float* __restrict__ pxw, const float* __restrict__ Whh,
    const float* __restrict__ h0p,
    float* __restrict__ y2, float* __restrict__ hn2) {
    const int d = blockIdx.x >> 5, sq = blockIdx.x & 31;
    const int tid = threadIdx.x;      // 0..767
    const int g   = tid >> 1;         // gate 0..383
    const int hf  = tid & 1;          // k-half
    __shared__ float hcur[HD];
    __shared__ float hwp[GD * 2];
    float w[64];
    const float* wrow = Whh + (size_t)(d * GD + g) * HD + hf * 64;
    #pragma unroll
    for (int k = 0; k < 64; ++k) w[k] = wrow[k];
    if (tid < HD) hcur[tid] = h0p[(d * 32 + sq) * HD + tid];

    float xr = 0.f, xz = 0.f, xn_ = 0.f;
    if (tid < HD) {
        const int p0 = d ? (PD - 1) : 0;
        const float* xw = pxw + (size_t)((d * PD + p0) * 32 + sq) * GD;
        xr = xw[tid]; xz = xw[HD + tid]; xn_ = xw[2 * HD + tid];
    }
    block_sync_lds();
    for (int t = 0; t < PD; ++t) {
        const int pp = d ? (PD - 1 - t) : t;
        float xrn = 0.f, xzn = 0.f, xnn = 0.f;
        if (t < PD - 1 && tid < HD) {
            const int pn = d ? (PD - 2 - t) : (t + 1);
            const float* xw = pxw + (size_t)((d * PD + pn) * 32 + sq) * GD;
            xrn = xw[tid]; xzn = xw[HD + tid]; xnn = xw[2 * HD + tid];
        }
        float a0 = 0.f, a1 = 0.f, a2 = 0.f, a3 = 0.f;
        const float* hb = &hcur[hf * 64];
        #pragma unroll
        for (int kc = 0; kc < 16; ++kc) {
            float4 h4 = *(const float4*)(hb + kc * 4);
            a0 += w[4 * kc + 0] * h4.x; a1 += w[4 * kc + 1] * h4.y;
            a2 += w[4 * kc + 2] * h4.z; a3 += w[4 * kc + 3] * h4.w;
        }
        hwp[tid] = (a0 + a1) + (a2 + a3);   // hwp[g*2+hf], linear: conflict-free
        block_sync_lds();
        if (tid < HD) {
            int uu = tid;
            float2 pr = *(const float2*)&hwp[2 * uu];
            float2 pz = *(const float2*)&hwp[2 * (HD + uu)];
            float2 pn_ = *(const float2*)&hwp[2 * (2 * HD + uu)];
            float r = sigm(xr + (pr.x + pr.y));
            float z = sigm(xz + (pz.x + pz.y));
            float nn = tanh_f(xn_ + r * (pn_.x + pn_.y));
            float hnew = (1.f - z) * nn + z * hcur[uu];
            hcur[uu] = hnew;
            y2[(pp * 32 + sq) * 256 + d * HD + uu] = hnew;  // not drained
        }
        block_sync_lds();
        xr = xrn; xz = xzn; xn_ = xnn;
    }
    if (tid < HD) hn2[(d * 32 + sq) * HD + tid] = hcur[tid];
}

// ---------------------------------------------------------------------------
// K4: packet attention + output head. v15: paWT coalesced o[h] phase.
// ---------------------------------------------------------------------------
__global__ __launch_bounds__(256) void pkt_attn_cls(
    const float* __restrict__ y2, const float* __restrict__ hn2,
    const float* __restrict__ paWT, const float* __restrict__ ab,
    const float* __restrict__ cW, const float* __restrict__ cb,
    float* __restrict__ out) {
    const int b = blockIdx.x;
    const int tid = threadIdx.x;
    __shared__ float yl2[32][257];
    __shared__ float hnl[256];
    __shared__ float red[256];
    __shared__ float scl[PD];
    __shared__ float awl[PD];
    __shared__ float ctxl[256];
    __shared__ float ol[HD];
    hnl[tid] = hn2[(((b >> 4) * 32) + 2 * (b & 15) + (tid >> 7)) * HD + (tid & 127)];
    for (int ch = 0; ch < 4; ++ch) {
        __syncthreads();
        for (int idx = tid; idx < 32 * 256; idx += 256) {
            int r = idx >> 8, c = idx & 255;
            yl2[r][c] = y2[((ch * 32 + r) * 32 + b) * 256 + c];
        }
        __syncthreads();
        {
            int r = tid >> 3, seg = tid & 7;
            float acc = 0.f;
            for (int i = 0; i < 32; ++i) {
                int c = seg * 32 + ((i + seg * 4) & 31);
                acc += yl2[r][c] * hnl[c];
            }
            red[tid] = acc;
        }
        __syncthreads();
        if (tid < 32) {
            float s = 0.f;
            #pragma unroll
            for (int k = 0; k < 8; ++k) s += red[tid * 8 + k];
            scl[ch * 32 + tid] = s;
        }
    }
    __syncthreads();
    if (tid < 64) {
        float s0 = scl[tid], s1 = scl[64 + tid];
        float m = fmaxf(s0, s1);
        #pragma unroll
        for (int o = 32; o; o >>= 1) m = fmaxf(m, __shfl_xor(m, o));
        float e0 = __expf(s0 - m), e1 = __expf(s1 - m);
        float ss = e0 + e1;
        #pragma unroll
        for (int o = 32; o; o >>= 1) ss += __shfl_xor(ss, o);
        awl[tid] = e0 / ss; awl[64 + tid] = e1 / ss;
    }
    __syncthreads();
    {
        int c = tid;
        float acc = 0.f;
        for (int p2 = 0; p2 < PD; ++p2) acc += awl[p2] * y2[(p2 * 32 + b) * 256 + c];
        ctxl[c] = acc;
    }
    __syncthreads();
    {   // o[h] partials: h per-lane -> coalesced paWT reads
        int h = tid & 127, hf = tid >> 7;
        float acc = 0.f;
        for (int c = hf * 128; c < hf * 128 + 128; ++c) acc += ctxl[c] * paWT[c * 128 + h];
        red[hf * 128 + h] = acc;
    }
    __syncthreads();
    if (tid < HD) ol[tid] = red[tid] + red[128 + tid] + ab[tid];
    __syncthreads();
    if (tid < 11) {
        float acc = cb[tid];
        for (int h = 0; h < HD; ++h) acc += ol[h] * cW[tid * HD + h];
        out[b * 11 + tid] = acc;
    }
}

// ---------------------------------------------------------------------------
extern "C" void kernel_launch(void* const* d_in, const int* in_sizes, int n_in,
                              void* d_out, int out_size, void* d_ws, size_t ws_size,
                              hipStream_t stream) {
    const int*   flow = (const int*)d_in[0];
    const float* emb  = (const float*)d_in[1];
    const float* bWih = (const float*)d_in[2];
    const float* bWhh = (const float*)d_in[3];
    const float* baW  = (const float*)d_in[4];
    const float* bab  = (const float*)d_in[5];
    const float* pWih = (const float*)d_in[6];
    const float* pWhh = (const float*)d_in[7];
    const float* paW  = (const float*)d_in[8];
    const float* pab  = (const float*)d_in[9];
    const float* cW   = (const float*)d_in[10];
    const float* cb   = (const float*)d_in[11];
    const float* h0b  = (const float*)d_in[12];
    const float* h0p  = (const float*)d_in[13];
    float* out = (float*)d_out;

    char* ws = (char*)d_ws;
    size_t off = 0;
    unsigned short* y = (unsigned short*)(ws + off); off += (size_t)SD * ND * 256 * 2; // 134 MiB
    float* hn    = (float*)(ws + off); off += (size_t)2 * ND * HD * 4;
    float* ctxg  = (float*)(ws + off); off += (size_t)ND * 256 * 4;                    // 4 MiB
    float* pxw   = (float*)(ws + off); off += (size_t)2 * PD * 32 * GD * 4;
    float* y2    = (float*)(ws + off); off += (size_t)PD * 32 * 256 * 4;
    float* hn2   = (float*)(ws + off); off += (size_t)2 * 32 * HD * 4;
    unsigned short* embHi = (unsigned short*)(ws + off); off += (size_t)VD * 64 * 2;   // 8.4 MiB
    float* aWT   = (float*)(ws + off); off += (size_t)256 * 64 * 4;
    float* pWT   = (float*)(ws + off); off += (size_t)2 * 64 * GD * 4;
    float* paWT  = (float*)(ws + off); off += (size_t)256 * HD * 4;
    if (ws_size < off) return;  // signature: output stays 0 => ws too small

    prep_all<<<(VD * 64 + 255) / 256, 256, 0, stream>>>(emb, embHi, baW, aWT, pWih, pWT, paW, paWT);
    byte_gru_mfma<<<256, 512, 0, stream>>>(flow, embHi, bWih, bWhh, h0b, y, hn);
    byte_attn<<<ND, 256, 0, stream>>>(y, hn, ctxg);
    enc_pxw<<<PD, 768, 0, stream>>>(ctxg, aWT, bab, pWT, pxw);
    pkt_gru<<<64, 768, 0, stream>>>(pxw, pWhh, h0p, y2, hn2);
    pkt_attn_cls<<<32, 256, 0, stream>>>(y2, hn2, paWT, pab, cW, cb, out);
}

// Round 16
// 484.125 us; speedup vs baseline: 1.2613x; 1.2613x over previous
//
#include <hip/hip_runtime.h>
#include <hip/hip_bf16.h>

// Problem dims (fixed by reference)
#define PD 128   // packets
#define BD 32    // batch
#define SD 64    // bytes per packet (byte-GRU seq len)
#define ED 50    // embedding size
#define HD 128   // hidden (byte and packet)
#define GD 384   // 3*H gates
#define ND 4096  // P*B byte-level batch
#define VD 65536 // vocab
#define LW 128   // LDS row stride in u16 (measured optimum: r7 ladder)

typedef __attribute__((ext_vector_type(8))) short bf16x8;
typedef __attribute__((ext_vector_type(4))) float f32x4;

__device__ __forceinline__ float sigm(float x) { return 1.0f / (1.0f + __expf(-x)); }
__device__ __forceinline__ float tanh_f(float x) { return 1.0f - 2.0f / (__expf(2.0f * x) + 1.0f); }

__device__ __forceinline__ unsigned short f2b(float f) {  // f32 -> bf16 raw, RNE
    union { float f; unsigned u; } a; a.f = f;
    unsigned r = a.u + 0x7FFFu + ((a.u >> 16) & 1u);
    return (unsigned short)(r >> 16);
}
__device__ __forceinline__ float b2f(unsigned short h) {
    union { unsigned u; float f; } a; a.u = ((unsigned)h) << 16; return a.f;
}

union frag_u { bf16x8 v; unsigned short s[8]; };

__device__ __forceinline__ void pin_v(bf16x8& v) { asm volatile("" : "+v"(v)); }

#define MFMA(acc, a, b) acc = __builtin_amdgcn_mfma_f32_16x16x32_bf16(a, b, acc, 0, 0, 0)

// Raw LDS-only barrier: does NOT drain vmcnt (global stores stay in flight).
__device__ __forceinline__ void block_sync_lds() {
    asm volatile("s_waitcnt lgkmcnt(0)" ::: "memory");
    __builtin_amdgcn_sched_barrier(0);
    __builtin_amdgcn_s_barrier();
    __builtin_amdgcn_sched_barrier(0);
}

// ---------------------------------------------------------------------------
// Prep: emb pad+convert; TRANSPOSED weights for coalesced reads.
//   aWT [c][e] (256x64), pWT [d][e][g] (2x64x384), paWT [c][h] (256x128)
// ---------------------------------------------------------------------------
__global__ void prep_all(const float* __restrict__ emb, unsigned short* __restrict__ embHi,
                         const float* __restrict__ aW, float* __restrict__ aWT,
                         const float* __restrict__ pWih, float* __restrict__ pWT,
                         const float* __restrict__ paW, float* __restrict__ paWT) {
    int idx = blockIdx.x * 256 + threadIdx.x;
    if (idx < VD * 64) {
        int row = idx >> 6, e = idx & 63;
        float v = (e < ED) ? emb[row * ED + e] : 0.f;
        embHi[idx] = f2b(v);
    }
    if (idx < 256 * 64) {
        int c = idx >> 6, e = idx & 63;
        aWT[idx] = (e < ED) ? aW[e * 256 + c] : 0.f;
    }
    if (idx < 2 * 64 * GD) {
        int g = idx % GD, r = idx / GD;   // r = d*64+e
        int d = r >> 6, e = r & 63;
        pWT[idx] = (e < ED) ? pWih[((size_t)(d * GD + g)) * ED + e] : 0.f;
    }
    if (idx < 256 * HD) {                 // paWT[c*128+h]
        int c = idx >> 7, h = idx & 127;
        paWT[idx] = paW[h * 256 + c];
    }
}

// ---------------------------------------------------------------------------
// K1: byte-level bi-GRU via MFMA, split-bf16 precision compensation.
// (r11/r13 structure exactly: plateau config, best measured.)
// ---------------------------------------------------------------------------
__global__ __attribute__((amdgpu_flat_work_group_size(512, 512), amdgpu_waves_per_eu(2, 2)))
void byte_gru_mfma(
    const int* __restrict__ flow, const unsigned short* __restrict__ embHi,
    const float* __restrict__ Wih, const float* __restrict__ Whh,
    const float* __restrict__ h0b,
    unsigned short* __restrict__ y, float* __restrict__ hn) {
    const int dir   = blockIdx.x >> 7;
    const int chunk = blockIdx.x & 127;
    const int n0    = chunk * 32;
    const int tid   = threadIdx.x;
    const int w     = tid >> 6;
    const int lane  = tid & 63;
    const int col   = lane & 15;
    const int kq    = lane >> 4;
    const int u     = w * 16 + col;

    __shared__ unsigned short HHI[2][32 * LW];
    __shared__ unsigned short HLO[2][32 * LW];
    __shared__ int FLOWT[SD * 32];

    const int yrow = tid >> 4;
    const int yu0  = (tid & 15) * 8;
    const int ysw  = yrow * LW + (yu0 ^ ((yrow & 7) << 3));

    bf16x8 WHh[3][4], WHl[3][4], WXh[3][2], WXl[3][2];
    {
        const float* WhhD = Whh + dir * GD * HD;
        #pragma unroll
        for (int g3 = 0; g3 < 3; ++g3) {
            const float* row = WhhD + (g3 * HD + u) * HD;
            #pragma unroll
            for (int kt = 0; kt < 4; ++kt) {
                const int k0 = kt * 32 + kq * 8;
                frag_u h_, l_;
                #pragma unroll
                for (int b = 0; b < 8; ++b) {
                    float v = row[k0 + b];
                    unsigned short hi = f2b(v);
                    h_.s[b] = hi; l_.s[b] = f2b(v - b2f(hi));
                }
                WHh[g3][kt] = h_.v; WHl[g3][kt] = l_.v;
                pin_v(WHh[g3][kt]); pin_v(WHl[g3][kt]);
            }
        }
        const float* WihD = Wih + dir * GD * ED;
        #pragma unroll
        for (int g3 = 0; g3 < 3; ++g3) {
            const float* row = WihD + (g3 * HD + u) * ED;
            #pragma unroll
            for (int kx = 0; kx < 2; ++kx) {
                const int k0 = kx * 32 + kq * 8;
                frag_u h_, l_;
                #pragma unroll
                for (int b = 0; b < 8; ++b) {
                    const int e = k0 + b;
                    float v = (e < ED) ? row[e] : 0.f;
                    unsigned short hi = f2b(v);
                    h_.s[b] = hi; l_.s[b] = f2b(v - b2f(hi));
                }
                WXh[g3][kx] = h_.v; WXl[g3][kx] = l_.v;
                pin_v(WXh[g3][kx]); pin_v(WXl[g3][kx]);
            }
        }
    }

    float hreg[2][4];
    {
        const float* h0row = h0b + (size_t)((chunk * 2 + dir) * 32) * HD;
        #pragma unroll
        for (int m = 0; m < 2; ++m)
            #pragma unroll
            for (int j = 0; j < 4; ++j)
                hreg[m][j] = h0row[(m * 16 + kq * 4 + j) * HD + u];
        for (int idx = tid; idx < 32 * HD; idx += 512) {
            int seq = idx >> 7, uu = idx & 127;
            float v = h0row[idx];
            unsigned short hi = f2b(v);
            int sw = seq * LW + (uu ^ ((seq & 7) << 3));
            HHI[0][sw] = hi; HLO[0][sw] = f2b(v - b2f(hi));
        }
        for (int j = tid; j < SD * 32; j += 512) {
            int s = j >> 5, seq = j & 31;
            FLOWT[j] = flow[(n0 + seq) * SD + s];
        }
    }
    block_sync_lds();

    bf16x8 xa00, xa01, xa10, xa11;
    {
        const int s0 = dir ? (SD - 1) : 0;
        int i0 = FLOWT[s0 * 32 + col];
        int i1 = FLOWT[s0 * 32 + 16 + col];
        const bf16x8* r0 = (const bf16x8*)(embHi + (size_t)i0 * 64);
        const bf16x8* r1 = (const bf16x8*)(embHi + (size_t)i1 * 64);
        xa00 = r0[kq]; xa01 = r0[4 + kq];
        xa10 = r1[kq]; xa11 = r1[4 + kq];
    }

    int par = 0;
    for (int t = 0; t < SD; ++t) {
        const int s = dir ? (SD - 1 - t) : t;

        if (t > 0) {
            const int sp = dir ? (SD - t) : (t - 1);
            uint4 v = *(const uint4*)&HHI[par][ysw];
            *(uint4*)&y[((size_t)(sp * ND) + n0 + yrow) * 256 + dir * HD + yu0] = v;
        }

        bf16x8 xn00, xn01, xn10, xn11;
        if (t < SD - 1) {
            const int sn = dir ? (SD - 2 - t) : (t + 1);
            int i0 = FLOWT[sn * 32 + col];
            int i1 = FLOWT[sn * 32 + 16 + col];
            const bf16x8* r0 = (const bf16x8*)(embHi + (size_t)i0 * 64);
            const bf16x8* r1 = (const bf16x8*)(embHi + (size_t)i1 * 64);
            xn00 = r0[kq]; xn01 = r0[4 + kq];
            xn10 = r1[kq]; xn11 = r1[4 + kq];
        }

        f32x4 aR[2], aZ[2], aHN[2], aXN[2];
        const f32x4 zero = {0.f, 0.f, 0.f, 0.f};
        #pragma unroll
        for (int m = 0; m < 2; ++m) { aR[m] = zero; aZ[m] = zero; aHN[m] = zero; aXN[m] = zero; }

        const unsigned short* HHIp = HHI[par];
        const unsigned short* HLOp = HLO[par];
        #pragma unroll
        for (int kt = 0; kt < 4; ++kt) {
            const int off = kt * 32 + kq * 8;
            const int sw0 = col * LW + (off ^ ((col & 7) << 3));
            const int sw1 = sw0 + 16 * LW;
            bf16x8 ah0 = *(const bf16x8*)&HHIp[sw0];
            bf16x8 al0 = *(const bf16x8*)&HLOp[sw0];
            bf16x8 ah1 = *(const bf16x8*)&HHIp[sw1];
            bf16x8 al1 = *(const bf16x8*)&HLOp[sw1];
            MFMA(aR[0], ah0, WHh[0][kt]); MFMA(aR[0], al0, WHh[0][kt]); MFMA(aR[0], ah0, WHl[0][kt]);
            MFMA(aZ[0], ah0, WHh[1][kt]); MFMA(aZ[0], al0, WHh[1][kt]); MFMA(aZ[0], ah0, WHl[1][kt]);
            MFMA(aHN[0], ah0, WHh[2][kt]); MFMA(aHN[0], al0, WHh[2][kt]); MFMA(aHN[0], ah0, WHl[2][kt]);
            MFMA(aR[1], ah1, WHh[0][kt]); MFMA(aR[1], al1, WHh[0][kt]); MFMA(aR[1], ah1, WHl[0][kt]);
            MFMA(aZ[1], ah1, WHh[1][kt]); MFMA(aZ[1], al1, WHh[1][kt]); MFMA(aZ[1], ah1, WHl[1][kt]);
            MFMA(aHN[1], ah1, WHh[2][kt]); MFMA(aHN[1], al1, WHh[2][kt]); MFMA(aHN[1], ah1, WHl[2][kt]);
        }
        #pragma unroll
        for (int kx = 0; kx < 2; ++kx) {
            bf16x8 x0 = kx ? xa01 : xa00;
            bf16x8 x1 = kx ? xa11 : xa10;
            MFMA(aR[0], x0, WXh[0][kx]); MFMA(aR[0], x0, WXl[0][kx]);
            MFMA(aZ[0], x0, WXh[1][kx]); MFMA(aZ[0], x0, WXl[1][kx]);
            MFMA(aXN[0], x0, WXh[2][kx]); MFMA(aXN[0], x0, WXl[2][kx]);
            MFMA(aR[1], x1, WXh[0][kx]); MFMA(aR[1], x1, WXl[0][kx]);
            MFMA(aZ[1], x1, WXh[1][kx]); MFMA(aZ[1], x1, WXl[1][kx]);
            MFMA(aXN[1], x1, WXh[2][kx]); MFMA(aXN[1], x1, WXl[2][kx]);
        }

        unsigned short* HHIn = HHI[par ^ 1];
        unsigned short* HLOn = HLO[par ^ 1];
        #pragma unroll
        for (int m = 0; m < 2; ++m)
            #pragma unroll
            for (int j = 0; j < 4; ++j) {
                float r = sigm(aR[m][j]);
                float z = sigm(aZ[m][j]);
                float nn = tanh_f(aXN[m][j] + r * aHN[m][j]);
                float hnew = (1.f - z) * nn + z * hreg[m][j];
                hreg[m][j] = hnew;
                __hip_bfloat16 bh = __float2bfloat16(hnew);
                unsigned short hi = *(unsigned short*)&bh;
                __hip_bfloat16 bl = __float2bfloat16(hnew - b2f(hi));
                const int seq = m * 16 + kq * 4 + j;
                const int sw = seq * LW + (u ^ ((seq & 7) << 3));
                HHIn[sw] = hi;
                HLOn[sw] = *(unsigned short*)&bl;
            }
        block_sync_lds();
        xa00 = xn00; xa01 = xn01; xa10 = xn10; xa11 = xn11;
        par ^= 1;
    }
    {
        const int sl = dir ? 0 : (SD - 1);
        uint4 v = *(const uint4*)&HHI[par][ysw];
        *(uint4*)&y[((size_t)(sl * ND) + n0 + yrow) * 256 + dir * HD + yu0] = v;
    }
    #pragma unroll
    for (int m = 0; m < 2; ++m)
        #pragma unroll
        for (int j = 0; j < 4; ++j) {
            int seq = m * 16 + kq * 4 + j;
            hn[((size_t)dir * ND + n0 + seq) * HD + u] = hreg[m][j];
        }
}

// ---------------------------------------------------------------------------
// K2: byte attention + enc projection + fused pkt-GRU input projection.
// (r14 structure exactly: best measured. r15's hoist regressed via
// runtime-indexed register array -> scratch.)
// ---------------------------------------------------------------------------
__global__ __launch_bounds__(256) void byte_attn(
    const unsigned short* __restrict__ y, const float* __restrict__ hn,
    const float* __restrict__ aWT, const float* __restrict__ ab,
    const float* __restrict__ pWT, float* __restrict__ pxw) {
    const int n = blockIdx.x;
    const int p = n >> 5, irow = n & 31;
    const int tid = threadIdx.x;
    __shared__ unsigned short yl[SD][256];
    __shared__ float hnl[256];
    __shared__ float red[256];
    __shared__ float red2[256];
    __shared__ float awl[SD];
    __shared__ float ctxl[256];
    __shared__ float encl[64];

    for (int idx = tid; idx < SD * 32; idx += 256) {
        int s = idx >> 5, cc = (idx & 31) * 8;
        *(uint4*)&yl[s][cc] = *(const uint4*)&y[((s * ND) + n) * 256 + cc];
    }
    {   // hn_p reshape quirk: flat idx = irow*256+c over (2,32,128)
        int c = tid;
        int idx = irow * 256 + c;
        int d = idx >> 12, bb = (idx >> 7) & 31, uu = idx & 127;
        hnl[c] = hn[(d * ND + p * 32 + bb) * HD + uu];
    }
    __syncthreads();
    {   // scores: 2-wide, skewed to spread banks
        int s = tid & 63, grp = tid >> 6;
        float acc = 0.f;
        for (int k = 0; k < 32; ++k) {
            int c2 = grp * 32 + ((s + k) & 31);
            unsigned pair = *(const unsigned*)&yl[s][c2 * 2];
            float2 hv = *(const float2*)&hnl[c2 * 2];
            union { unsigned u; float f; } lo, hi;
            lo.u = pair << 16; hi.u = pair & 0xFFFF0000u;
            acc += lo.f * hv.x + hi.f * hv.y;
        }
        red[grp * 64 + s] = acc;
    }
    __syncthreads();
    if (tid < 64) {
        float sc = red[tid] + red[64 + tid] + red[128 + tid] + red[192 + tid];
        float m = sc;
        #pragma unroll
        for (int o = 32; o; o >>= 1) m = fmaxf(m, __shfl_xor(m, o));
        float e = __expf(sc - m);
        float ssum = e;
        #pragma unroll
        for (int o = 32; o; o >>= 1) ssum += __shfl_xor(ssum, o);
        awl[tid] = e / ssum;
    }
    __syncthreads();
    {   // ctx: thread = (column-pair c2, s-half sh); 32 x ds_read_b32 each
        int c2 = tid & 127, sh = tid >> 7;
        float a0 = 0.f, a1 = 0.f;
        const int s0 = sh * 32;
        for (int s = s0; s < s0 + 32; ++s) {
            unsigned pair = *(const unsigned*)&yl[s][c2 * 2];
            union { unsigned u; float f; } lo, hi;
            lo.u = pair << 16; hi.u = pair & 0xFFFF0000u;
            float aw = awl[s];
            a0 += aw * lo.f; a1 += aw * hi.f;
        }
        float* dst = sh ? red2 : red;
        *(float2*)&dst[c2 * 2] = make_float2(a0, a1);
    }
    __syncthreads();
    ctxl[tid] = red[tid] + red2[tid];
    __syncthreads();
    {   // enc[e] partials: coalesced aWT reads
        int e = tid & 63, q = tid >> 6;
        float acc = 0.f;
        for (int c = q * 64; c < q * 64 + 64; ++c) acc += ctxl[c] * aWT[c * 64 + e];
        red[q * 64 + e] = acc;
    }
    __syncthreads();
    if (tid < 64) {
        float v = red[tid] + red[64 + tid] + red[128 + tid] + red[192 + tid];
        encl[tid] = (tid < ED) ? (v + ab[tid]) : 0.f;
    }
    __syncthreads();
    {   // fused pkt_xw: 3 gates per thread, encl loads shared
        int fg0 = tid, fg1 = tid + 256, fg2 = tid + 512;
        int d0 = fg0 >= GD, d1 = fg1 >= GD, d2 = fg2 >= GD;
        int g0 = fg0 - d0 * GD, g1 = fg1 - d1 * GD, g2 = fg2 - d2 * GD;
        const float* wr0 = pWT + (size_t)(d0 * 64) * GD + g0;
        const float* wr1 = pWT + (size_t)(d1 * 64) * GD + g1;
        const float* wr2 = pWT + (size_t)(d2 * 64) * GD + g2;
        float a0 = 0.f, a1 = 0.f, a2 = 0.f;
        #pragma unroll 2
        for (int e = 0; e < ED; ++e) {
            float ev = encl[e];
            size_t o = (size_t)e * GD;
            a0 += ev * wr0[o]; a1 += ev * wr1[o]; a2 += ev * wr2[o];
        }
        pxw[((size_t)(d0 * PD + p) * 32 + irow) * GD + g0] = a0;
        pxw[((size_t)(d1 * PD + p) * 32 + irow) * GD + g1] = a1;
        pxw[((size_t)(d2 * PD + p) * 32 + irow) * GD + g2] = a2;
    }
}

// ---------------------------------------------------------------------------
// K3: packet-level bi-GRU. (r13 split-K structure: best measured.)
// ---------------------------------------------------------------------------
__global__ __launch_bounds__(768, 1) void pkt_gru(
    const float* __restrict__ pxw, const float* __restrict__ Whh,
    const float* __restrict__ h0p,
    float* __restrict__ y2, float* __restrict__ hn2) {
    const int d = blockIdx.x >> 5, sq = blockIdx.x & 31;
    const int tid = threadIdx.x;      // 0..767
    const int g   = tid >> 1;         // gate 0..383
    const int hf  = tid & 1;          // k-half
    __shared__ float hcur[HD];
    __shared__ float hwp[GD * 2];
    float w[64];
    const float* wrow = Whh + (size_t)(d * GD + g) * HD + hf * 64;
    #pragma unroll
    for (int k = 0; k < 64; ++k) w[k] = wrow[k];
    if (tid < HD) hcur[tid] = h0p[(d * 32 + sq) * HD + tid];

    float xr = 0.f, xz = 0.f, xn_ = 0.f;
    if (tid < HD) {
        const int p0 = d ? (PD - 1) : 0;
        const float* xw = pxw + (size_t)((d * PD + p0) * 32 + sq) * GD;
        xr = xw[tid]; xz = xw[HD + tid]; xn_ = xw[2 * HD + tid];
    }
    block_sync_lds();
    for (int t = 0; t < PD; ++t) {
        const int pp = d ? (PD - 1 - t) : t;
        float xrn = 0.f, xzn = 0.f, xnn = 0.f;
        if (t < PD - 1 && tid < HD) {
            const int pn = d ? (PD - 2 - t) : (t + 1);
            const float* xw = pxw + (size_t)((d * PD + pn) * 32 + sq) * GD;
            xrn = xw[tid]; xzn = xw[HD + tid]; xnn = xw[2 * HD + tid];
        }
        float a0 = 0.f, a1 = 0.f, a2 = 0.f, a3 = 0.f;
        const float* hb = &hcur[hf * 64];
        #pragma unroll
        for (int kc = 0; kc < 16; ++kc) {
            float4 h4 = *(const float4*)(hb + kc * 4);
            a0 += w[4 * kc + 0] * h4.x; a1 += w[4 * kc + 1] * h4.y;
            a2 += w[4 * kc + 2] * h4.z; a3 += w[4 * kc + 3] * h4.w;
        }
        hwp[tid] = (a0 + a1) + (a2 + a3);   // hwp[g*2+hf], linear: conflict-free
        block_sync_lds();
        if (tid < HD) {
            int uu = tid;
            float2 pr = *(const float2*)&hwp[2 * uu];
            float2 pz = *(const float2*)&hwp[2 * (HD + uu)];
            float2 pn_ = *(const float2*)&hwp[2 * (2 * HD + uu)];
            float r = sigm(xr + (pr.x + pr.y));
            float z = sigm(xz + (pz.x + pz.y));
            float nn = tanh_f(xn_ + r * (pn_.x + pn_.y));
            float hnew = (1.f - z) * nn + z * hcur[uu];
            hcur[uu] = hnew;
            y2[(pp * 32 + sq) * 256 + d * HD + uu] = hnew;  // not drained
        }
        block_sync_lds();
        xr = xrn; xz = xzn; xn_ = xnn;
    }
    if (tid < HD) hn2[(d * 32 + sq) * HD + tid] = hcur[tid];
}

// ---------------------------------------------------------------------------
// K4: packet attention + output head. v16: paWT coalesced o[h] phase
// (h per-lane -> one 512B line per load; was 32-line gather x 128 iters).
// ---------------------------------------------------------------------------
__global__ __launch_bounds__(256) void pkt_attn_cls(
    const float* __restrict__ y2, const float* __restrict__ hn2,
    const float* __restrict__ paWT, const float* __restrict__ ab,
    const float* __restrict__ cW, const float* __restrict__ cb,
    float* __restrict__ out) {
    const int b = blockIdx.x;
    const int tid = threadIdx.x;
    __shared__ float yl2[32][257];
    __shared__ float hnl[256];
    __shared__ float red[256];
    __shared__ float scl[PD];
    __shared__ float awl[PD];
    __shared__ float ctxl[256];
    __shared__ float ol[HD];
    hnl[tid] = hn2[(((b >> 4) * 32) + 2 * (b & 15) + (tid >> 7)) * HD + (tid & 127)];
    for (int ch = 0; ch < 4; ++ch) {
        __syncthreads();
        for (int idx = tid; idx < 32 * 256; idx += 256) {
            int r = idx >> 8, c = idx & 255;
            yl2[r][c] = y2[((ch * 32 + r) * 32 + b) * 256 + c];
        }
        __syncthreads();
        {
            int r = tid >> 3, seg = tid & 7;
            float acc = 0.f;
            for (int i = 0; i < 32; ++i) {
                int c = seg * 32 + ((i + seg * 4) & 31);
                acc += yl2[r][c] * hnl[c];
            }
            red[tid] = acc;
        }
        __syncthreads();
        if (tid < 32) {
            float s = 0.f;
            #pragma unroll
            for (int k = 0; k < 8; ++k) s += red[tid * 8 + k];
            scl[ch * 32 + tid] = s;
        }
    }
    __syncthreads();
    if (tid < 64) {
        float s0 = scl[tid], s1 = scl[64 + tid];
        float m = fmaxf(s0, s1);
        #pragma unroll
        for (int o = 32; o; o >>= 1) m = fmaxf(m, __shfl_xor(m, o));
        float e0 = __expf(s0 - m), e1 = __expf(s1 - m);
        float ss = e0 + e1;
        #pragma unroll
        for (int o = 32; o; o >>= 1) ss += __shfl_xor(ss, o);
        awl[tid] = e0 / ss; awl[64 + tid] = e1 / ss;
    }
    __syncthreads();
    {
        int c = tid;
        float acc = 0.f;
        for (int p2 = 0; p2 < PD; ++p2) acc += awl[p2] * y2[(p2 * 32 + b) * 256 + c];
        ctxl[c] = acc;
    }
    __syncthreads();
    {   // o[h] partials: h per-lane -> coalesced paWT reads
        int h = tid & 127, hf = tid >> 7;
        float acc = 0.f;
        for (int c = hf * 128; c < hf * 128 + 128; ++c) acc += ctxl[c] * paWT[c * 128 + h];
        red[hf * 128 + h] = acc;
    }
    __syncthreads();
    if (tid < HD) ol[tid] = red[tid] + red[128 + tid] + ab[tid];
    __syncthreads();
    if (tid < 11) {
        float acc = cb[tid];
        for (int h = 0; h < HD; ++h) acc += ol[h] * cW[tid * HD + h];
        out[b * 11 + tid] = acc;
    }
}

// ---------------------------------------------------------------------------
extern "C" void kernel_launch(void* const* d_in, const int* in_sizes, int n_in,
                              void* d_out, int out_size, void* d_ws, size_t ws_size,
                              hipStream_t stream) {
    const int*   flow = (const int*)d_in[0];
    const float* emb  = (const float*)d_in[1];
    const float* bWih = (const float*)d_in[2];
    const float* bWhh = (const float*)d_in[3];
    const float* baW  = (const float*)d_in[4];
    const float* bab  = (const float*)d_in[5];
    const float* pWih = (const float*)d_in[6];
    const float* pWhh = (const float*)d_in[7];
    const float* paW  = (const float*)d_in[8];
    const float* pab  = (const float*)d_in[9];
    const float* cW   = (const float*)d_in[10];
    const float* cb   = (const float*)d_in[11];
    const float* h0b  = (const float*)d_in[12];
    const float* h0p  = (const float*)d_in[13];
    float* out = (float*)d_out;

    char* ws = (char*)d_ws;
    size_t off = 0;
    unsigned short* y = (unsigned short*)(ws + off); off += (size_t)SD * ND * 256 * 2; // 134 MiB
    float* hn    = (float*)(ws + off); off += (size_t)2 * ND * HD * 4;
    float* pxw   = (float*)(ws + off); off += (size_t)2 * PD * 32 * GD * 4;
    float* y2    = (float*)(ws + off); off += (size_t)PD * 32 * 256 * 4;
    float* hn2   = (float*)(ws + off); off += (size_t)2 * 32 * HD * 4;
    unsigned short* embHi = (unsigned short*)(ws + off); off += (size_t)VD * 64 * 2;   // 8.4 MiB
    float* aWT   = (float*)(ws + off); off += (size_t)256 * 64 * 4;
    float* pWT   = (float*)(ws + off); off += (size_t)2 * 64 * GD * 4;
    float* paWT  = (float*)(ws + off); off += (size_t)256 * HD * 4;
    if (ws_size < off) return;  // signature: output stays 0 => ws too small

    prep_all<<<(VD * 64 + 255) / 256, 256, 0, stream>>>(emb, embHi, baW, aWT, pWih, pWT, paW, paWT);
    byte_gru_mfma<<<256, 512, 0, stream>>>(flow, embHi, bWih, bWhh, h0b, y, hn);
    byte_attn<<<ND, 256, 0, stream>>>(y, hn, aWT, bab, pWT, pxw);
    pkt_gru<<<64, 768, 0, stream>>>(pxw, pWhh, h0p, y2, hn2);
    pkt_attn_cls<<<32, 256, 0, stream>>>(y2, hn2, paWT, pab, cW, cb, out);
}

// Round 17
// 456.726 us; speedup vs baseline: 1.3370x; 1.0600x over previous
//
#include <hip/hip_runtime.h>
#include <hip/hip_bf16.h>

// Problem dims (fixed by reference)
#define PD 128   // packets
#define BD 32    // batch
#define SD 64    // bytes per packet (byte-GRU seq len)
#define ED 50    // embedding size
#define HD 128   // hidden (byte and packet)
#define GD 384   // 3*H gates
#define ND 4096  // P*B byte-level batch
#define VD 65536 // vocab
#define LW 128   // LDS row stride in u16 (measured optimum: r7 ladder)

typedef __attribute__((ext_vector_type(8))) short bf16x8;
typedef __attribute__((ext_vector_type(4))) float f32x4;

__device__ __forceinline__ float sigm(float x) { return 1.0f / (1.0f + __expf(-x)); }
__device__ __forceinline__ float tanh_f(float x) { return 1.0f - 2.0f / (__expf(2.0f * x) + 1.0f); }

__device__ __forceinline__ unsigned short f2b(float f) {  // f32 -> bf16 raw, RNE
    union { float f; unsigned u; } a; a.f = f;
    unsigned r = a.u + 0x7FFFu + ((a.u >> 16) & 1u);
    return (unsigned short)(r >> 16);
}
__device__ __forceinline__ float b2f(unsigned short h) {
    union { unsigned u; float f; } a; a.u = ((unsigned)h) << 16; return a.f;
}

union frag_u { bf16x8 v; unsigned short s[8]; };

__device__ __forceinline__ void pin_v(bf16x8& v) { asm volatile("" : "+v"(v)); }

#define MFMA(acc, a, b) acc = __builtin_amdgcn_mfma_f32_16x16x32_bf16(a, b, acc, 0, 0, 0)

// Raw LDS-only barrier: does NOT drain vmcnt (global stores stay in flight).
__device__ __forceinline__ void block_sync_lds() {
    asm volatile("s_waitcnt lgkmcnt(0)" ::: "memory");
    __builtin_amdgcn_sched_barrier(0);
    __builtin_amdgcn_s_barrier();
    __builtin_amdgcn_sched_barrier(0);
}

// ---------------------------------------------------------------------------
// Prep: emb pad+convert; TRANSPOSED attn/packet weights for coalesced reads.
// ---------------------------------------------------------------------------
__global__ void prep_all(const float* __restrict__ emb, unsigned short* __restrict__ embHi,
                         const float* __restrict__ aW, float* __restrict__ aWT,
                         const float* __restrict__ pWih, float* __restrict__ pWT) {
    int idx = blockIdx.x * 256 + threadIdx.x;
    if (idx < VD * 64) {
        int row = idx >> 6, e = idx & 63;
        float v = (e < ED) ? emb[row * ED + e] : 0.f;
        embHi[idx] = f2b(v);
    }
    if (idx < 256 * 64) {
        int c = idx >> 6, e = idx & 63;
        aWT[idx] = (e < ED) ? aW[e * 256 + c] : 0.f;
    }
    if (idx < 2 * 64 * GD) {
        int g = idx % GD, r = idx / GD;   // r = d*64+e
        int d = r >> 6, e = r & 63;
        pWT[idx] = (e < ED) ? pWih[((size_t)(d * GD + g)) * ED + e] : 0.f;
    }
}

// ---------------------------------------------------------------------------
// K1: byte-level bi-GRU via MFMA, split-bf16 precision compensation.
// (r11/r13 structure exactly: plateau config, best measured.)
// ---------------------------------------------------------------------------
__global__ __attribute__((amdgpu_flat_work_group_size(512, 512), amdgpu_waves_per_eu(2, 2)))
void byte_gru_mfma(
    const int* __restrict__ flow, const unsigned short* __restrict__ embHi,
    const float* __restrict__ Wih, const float* __restrict__ Whh,
    const float* __restrict__ h0b,
    unsigned short* __restrict__ y, float* __restrict__ hn) {
    const int dir   = blockIdx.x >> 7;
    const int chunk = blockIdx.x & 127;
    const int n0    = chunk * 32;
    const int tid   = threadIdx.x;
    const int w     = tid >> 6;
    const int lane  = tid & 63;
    const int col   = lane & 15;
    const int kq    = lane >> 4;
    const int u     = w * 16 + col;

    __shared__ unsigned short HHI[2][32 * LW];
    __shared__ unsigned short HLO[2][32 * LW];
    __shared__ int FLOWT[SD * 32];

    const int yrow = tid >> 4;
    const int yu0  = (tid & 15) * 8;
    const int ysw  = yrow * LW + (yu0 ^ ((yrow & 7) << 3));

    bf16x8 WHh[3][4], WHl[3][4], WXh[3][2], WXl[3][2];
    {
        const float* WhhD = Whh + dir * GD * HD;
        #pragma unroll
        for (int g3 = 0; g3 < 3; ++g3) {
            const float* row = WhhD + (g3 * HD + u) * HD;
            #pragma unroll
            for (int kt = 0; kt < 4; ++kt) {
                const int k0 = kt * 32 + kq * 8;
                frag_u h_, l_;
                #pragma unroll
                for (int b = 0; b < 8; ++b) {
                    float v = row[k0 + b];
                    unsigned short hi = f2b(v);
                    h_.s[b] = hi; l_.s[b] = f2b(v - b2f(hi));
                }
                WHh[g3][kt] = h_.v; WHl[g3][kt] = l_.v;
                pin_v(WHh[g3][kt]); pin_v(WHl[g3][kt]);
            }
        }
        const float* WihD = Wih + dir * GD * ED;
        #pragma unroll
        for (int g3 = 0; g3 < 3; ++g3) {
            const float* row = WihD + (g3 * HD + u) * ED;
            #pragma unroll
            for (int kx = 0; kx < 2; ++kx) {
                const int k0 = kx * 32 + kq * 8;
                frag_u h_, l_;
                #pragma unroll
                for (int b = 0; b < 8; ++b) {
                    const int e = k0 + b;
                    float v = (e < ED) ? row[e] : 0.f;
                    unsigned short hi = f2b(v);
                    h_.s[b] = hi; l_.s[b] = f2b(v - b2f(hi));
                }
                WXh[g3][kx] = h_.v; WXl[g3][kx] = l_.v;
                pin_v(WXh[g3][kx]); pin_v(WXl[g3][kx]);
            }
        }
    }

    float hreg[2][4];
    {
        const float* h0row = h0b + (size_t)((chunk * 2 + dir) * 32) * HD;
        #pragma unroll
        for (int m = 0; m < 2; ++m)
            #pragma unroll
            for (int j = 0; j < 4; ++j)
                hreg[m][j] = h0row[(m * 16 + kq * 4 + j) * HD + u];
        for (int idx = tid; idx < 32 * HD; idx += 512) {
            int seq = idx >> 7, uu = idx & 127;
            float v = h0row[idx];
            unsigned short hi = f2b(v);
            int sw = seq * LW + (uu ^ ((seq & 7) << 3));
            HHI[0][sw] = hi; HLO[0][sw] = f2b(v - b2f(hi));
        }
        for (int j = tid; j < SD * 32; j += 512) {
            int s = j >> 5, seq = j & 31;
            FLOWT[j] = flow[(n0 + seq) * SD + s];
        }
    }
    block_sync_lds();

    bf16x8 xa00, xa01, xa10, xa11;
    {
        const int s0 = dir ? (SD - 1) : 0;
        int i0 = FLOWT[s0 * 32 + col];
        int i1 = FLOWT[s0 * 32 + 16 + col];
        const bf16x8* r0 = (const bf16x8*)(embHi + (size_t)i0 * 64);
        const bf16x8* r1 = (const bf16x8*)(embHi + (size_t)i1 * 64);
        xa00 = r0[kq]; xa01 = r0[4 + kq];
        xa10 = r1[kq]; xa11 = r1[4 + kq];
    }

    int par = 0;
    for (int t = 0; t < SD; ++t) {
        const int s = dir ? (SD - 1 - t) : t;

        if (t > 0) {
            const int sp = dir ? (SD - t) : (t - 1);
            uint4 v = *(const uint4*)&HHI[par][ysw];
            *(uint4*)&y[((size_t)(sp * ND) + n0 + yrow) * 256 + dir * HD + yu0] = v;
        }

        bf16x8 xn00, xn01, xn10, xn11;
        if (t < SD - 1) {
            const int sn = dir ? (SD - 2 - t) : (t + 1);
            int i0 = FLOWT[sn * 32 + col];
            int i1 = FLOWT[sn * 32 + 16 + col];
            const bf16x8* r0 = (const bf16x8*)(embHi + (size_t)i0 * 64);
            const bf16x8* r1 = (const bf16x8*)(embHi + (size_t)i1 * 64);
            xn00 = r0[kq]; xn01 = r0[4 + kq];
            xn10 = r1[kq]; xn11 = r1[4 + kq];
        }

        f32x4 aR[2], aZ[2], aHN[2], aXN[2];
        const f32x4 zero = {0.f, 0.f, 0.f, 0.f};
        #pragma unroll
        for (int m = 0; m < 2; ++m) { aR[m] = zero; aZ[m] = zero; aHN[m] = zero; aXN[m] = zero; }

        const unsigned short* HHIp = HHI[par];
        const unsigned short* HLOp = HLO[par];
        #pragma unroll
        for (int kt = 0; kt < 4; ++kt) {
            const int off = kt * 32 + kq * 8;
            const int sw0 = col * LW + (off ^ ((col & 7) << 3));
            const int sw1 = sw0 + 16 * LW;
            bf16x8 ah0 = *(const bf16x8*)&HHIp[sw0];
            bf16x8 al0 = *(const bf16x8*)&HLOp[sw0];
            bf16x8 ah1 = *(const bf16x8*)&HHIp[sw1];
            bf16x8 al1 = *(const bf16x8*)&HLOp[sw1];
            MFMA(aR[0], ah0, WHh[0][kt]); MFMA(aR[0], al0, WHh[0][kt]); MFMA(aR[0], ah0, WHl[0][kt]);
            MFMA(aZ[0], ah0, WHh[1][kt]); MFMA(aZ[0], al0, WHh[1][kt]); MFMA(aZ[0], ah0, WHl[1][kt]);
            MFMA(aHN[0], ah0, WHh[2][kt]); MFMA(aHN[0], al0, WHh[2][kt]); MFMA(aHN[0], ah0, WHl[2][kt]);
            MFMA(aR[1], ah1, WHh[0][kt]); MFMA(aR[1], al1, WHh[0][kt]); MFMA(aR[1], ah1, WHl[0][kt]);
            MFMA(aZ[1], ah1, WHh[1][kt]); MFMA(aZ[1], al1, WHh[1][kt]); MFMA(aZ[1], ah1, WHl[1][kt]);
            MFMA(aHN[1], ah1, WHh[2][kt]); MFMA(aHN[1], al1, WHh[2][kt]); MFMA(aHN[1], ah1, WHl[2][kt]);
        }
        #pragma unroll
        for (int kx = 0; kx < 2; ++kx) {
            bf16x8 x0 = kx ? xa01 : xa00;
            bf16x8 x1 = kx ? xa11 : xa10;
            MFMA(aR[0], x0, WXh[0][kx]); MFMA(aR[0], x0, WXl[0][kx]);
            MFMA(aZ[0], x0, WXh[1][kx]); MFMA(aZ[0], x0, WXl[1][kx]);
            MFMA(aXN[0], x0, WXh[2][kx]); MFMA(aXN[0], x0, WXl[2][kx]);
            MFMA(aR[1], x1, WXh[0][kx]); MFMA(aR[1], x1, WXl[0][kx]);
            MFMA(aZ[1], x1, WXh[1][kx]); MFMA(aZ[1], x1, WXl[1][kx]);
            MFMA(aXN[1], x1, WXh[2][kx]); MFMA(aXN[1], x1, WXl[2][kx]);
        }

        unsigned short* HHIn = HHI[par ^ 1];
        unsigned short* HLOn = HLO[par ^ 1];
        #pragma unroll
        for (int m = 0; m < 2; ++m)
            #pragma unroll
            for (int j = 0; j < 4; ++j) {
                float r = sigm(aR[m][j]);
                float z = sigm(aZ[m][j]);
                float nn = tanh_f(aXN[m][j] + r * aHN[m][j]);
                float hnew = (1.f - z) * nn + z * hreg[m][j];
                hreg[m][j] = hnew;
                __hip_bfloat16 bh = __float2bfloat16(hnew);
                unsigned short hi = *(unsigned short*)&bh;
                __hip_bfloat16 bl = __float2bfloat16(hnew - b2f(hi));
                const int seq = m * 16 + kq * 4 + j;
                const int sw = seq * LW + (u ^ ((seq & 7) << 3));
                HHIn[sw] = hi;
                HLOn[sw] = *(unsigned short*)&bl;
            }
        block_sync_lds();
        xa00 = xn00; xa01 = xn01; xa10 = xn10; xa11 = xn11;
        par ^= 1;
    }
    {
        const int sl = dir ? 0 : (SD - 1);
        uint4 v = *(const uint4*)&HHI[par][ysw];
        *(uint4*)&y[((size_t)(sl * ND) + n0 + yrow) * 256 + dir * HD + yu0] = v;
    }
    #pragma unroll
    for (int m = 0; m < 2; ++m)
        #pragma unroll
        for (int j = 0; j < 4; ++j) {
            int seq = m * 16 + kq * 4 + j;
            hn[((size_t)dir * ND + n0 + seq) * HD + u] = hreg[m][j];
        }
}

// ---------------------------------------------------------------------------
// K2: byte attention + enc projection + fused pkt-GRU input projection.
// (r14 structure exactly: best measured, 456us total.)
// ---------------------------------------------------------------------------
__global__ __launch_bounds__(256) void byte_attn(
    const unsigned short* __restrict__ y, const float* __restrict__ hn,
    const float* __restrict__ aWT, const float* __restrict__ ab,
    const float* __restrict__ pWT, float* __restrict__ pxw) {
    const int n = blockIdx.x;
    const int p = n >> 5, irow = n & 31;
    const int tid = threadIdx.x;
    __shared__ unsigned short yl[SD][256];
    __shared__ float hnl[256];
    __shared__ float red[256];
    __shared__ float red2[256];
    __shared__ float awl[SD];
    __shared__ float ctxl[256];
    __shared__ float encl[64];

    for (int idx = tid; idx < SD * 32; idx += 256) {
        int s = idx >> 5, cc = (idx & 31) * 8;
        *(uint4*)&yl[s][cc] = *(const uint4*)&y[((s * ND) + n) * 256 + cc];
    }
    {   // hn_p reshape quirk: flat idx = irow*256+c over (2,32,128)
        int c = tid;
        int idx = irow * 256 + c;
        int d = idx >> 12, bb = (idx >> 7) & 31, uu = idx & 127;
        hnl[c] = hn[(d * ND + p * 32 + bb) * HD + uu];
    }
    __syncthreads();
    {   // scores: 2-wide, skewed to spread banks
        int s = tid & 63, grp = tid >> 6;
        float acc = 0.f;
        for (int k = 0; k < 32; ++k) {
            int c2 = grp * 32 + ((s + k) & 31);
            unsigned pair = *(const unsigned*)&yl[s][c2 * 2];
            float2 hv = *(const float2*)&hnl[c2 * 2];
            union { unsigned u; float f; } lo, hi;
            lo.u = pair << 16; hi.u = pair & 0xFFFF0000u;
            acc += lo.f * hv.x + hi.f * hv.y;
        }
        red[grp * 64 + s] = acc;
    }
    __syncthreads();
    if (tid < 64) {
        float sc = red[tid] + red[64 + tid] + red[128 + tid] + red[192 + tid];
        float m = sc;
        #pragma unroll
        for (int o = 32; o; o >>= 1) m = fmaxf(m, __shfl_xor(m, o));
        float e = __expf(sc - m);
        float ssum = e;
        #pragma unroll
        for (int o = 32; o; o >>= 1) ssum += __shfl_xor(ssum, o);
        awl[tid] = e / ssum;
    }
    __syncthreads();
    {   // ctx: thread = (column-pair c2, s-half sh); 32 x ds_read_b32 each
        int c2 = tid & 127, sh = tid >> 7;
        float a0 = 0.f, a1 = 0.f;
        const int s0 = sh * 32;
        for (int s = s0; s < s0 + 32; ++s) {
            unsigned pair = *(const unsigned*)&yl[s][c2 * 2];
            union { unsigned u; float f; } lo, hi;
            lo.u = pair << 16; hi.u = pair & 0xFFFF0000u;
            float aw = awl[s];
            a0 += aw * lo.f; a1 += aw * hi.f;
        }
        float* dst = sh ? red2 : red;
        *(float2*)&dst[c2 * 2] = make_float2(a0, a1);
    }
    __syncthreads();
    ctxl[tid] = red[tid] + red2[tid];
    __syncthreads();
    {   // enc[e] partials: coalesced aWT reads
        int e = tid & 63, q = tid >> 6;
        float acc = 0.f;
        for (int c = q * 64; c < q * 64 + 64; ++c) acc += ctxl[c] * aWT[c * 64 + e];
        red[q * 64 + e] = acc;
    }
    __syncthreads();
    if (tid < 64) {
        float v = red[tid] + red[64 + tid] + red[128 + tid] + red[192 + tid];
        encl[tid] = (tid < ED) ? (v + ab[tid]) : 0.f;
    }
    __syncthreads();
    {   // fused pkt_xw: 3 gates per thread, encl loads shared
        int fg0 = tid, fg1 = tid + 256, fg2 = tid + 512;
        int d0 = fg0 >= GD, d1 = fg1 >= GD, d2 = fg2 >= GD;
        int g0 = fg0 - d0 * GD, g1 = fg1 - d1 * GD, g2 = fg2 - d2 * GD;
        const float* wr0 = pWT + (size_t)(d0 * 64) * GD + g0;
        const float* wr1 = pWT + (size_t)(d1 * 64) * GD + g1;
        const float* wr2 = pWT + (size_t)(d2 * 64) * GD + g2;
        float a0 = 0.f, a1 = 0.f, a2 = 0.f;
        #pragma unroll 2
        for (int e = 0; e < ED; ++e) {
            float ev = encl[e];
            size_t o = (size_t)e * GD;
            a0 += ev * wr0[o]; a1 += ev * wr1[o]; a2 += ev * wr2[o];
        }
        pxw[((size_t)(d0 * PD + p) * 32 + irow) * GD + g0] = a0;
        pxw[((size_t)(d1 * PD + p) * 32 + irow) * GD + g1] = a1;
        pxw[((size_t)(d2 * PD + p) * 32 + irow) * GD + g2] = a2;
    }
}

// ---------------------------------------------------------------------------
// K3: packet-level bi-GRU. (r13 split-K structure: best measured.)
// ---------------------------------------------------------------------------
__global__ __launch_bounds__(768, 1) void pkt_gru(
    const float* __restrict__ pxw, const float* __restrict__ Whh,
    const float* __restrict__ h0p,
    float* __restrict__ y2, float* __restrict__ hn2) {
    const int d = blockIdx.x >> 5, sq = blockIdx.x & 31;
    const int tid = threadIdx.x;      // 0..767
    const int g   = tid >> 1;         // gate 0..383
    const int hf  = tid & 1;          // k-half
    __shared__ float hcur[HD];
    __shared__ float hwp[GD * 2];
    float w[64];
    const float* wrow = Whh + (size_t)(d * GD + g) * HD + hf * 64;
    #pragma unroll
    for (int k = 0; k < 64; ++k) w[k] = wrow[k];
    if (tid < HD) hcur[tid] = h0p[(d * 32 + sq) * HD + tid];

    float xr = 0.f, xz = 0.f, xn_ = 0.f;
    if (tid < HD) {
        const int p0 = d ? (PD - 1) : 0;
        const float* xw = pxw + (size_t)((d * PD + p0) * 32 + sq) * GD;
        xr = xw[tid]; xz = xw[HD + tid]; xn_ = xw[2 * HD + tid];
    }
    block_sync_lds();
    for (int t = 0; t < PD; ++t) {
        const int pp = d ? (PD - 1 - t) : t;
        float xrn = 0.f, xzn = 0.f, xnn = 0.f;
        if (t < PD - 1 && tid < HD) {
            const int pn = d ? (PD - 2 - t) : (t + 1);
            const float* xw = pxw + (size_t)((d * PD + pn) * 32 + sq) * GD;
            xrn = xw[tid]; xzn = xw[HD + tid]; xnn = xw[2 * HD + tid];
        }
        float a0 = 0.f, a1 = 0.f, a2 = 0.f, a3 = 0.f;
        const float* hb = &hcur[hf * 64];
        #pragma unroll
        for (int kc = 0; kc < 16; ++kc) {
            float4 h4 = *(const float4*)(hb + kc * 4);
            a0 += w[4 * kc + 0] * h4.x; a1 += w[4 * kc + 1] * h4.y;
            a2 += w[4 * kc + 2] * h4.z; a3 += w[4 * kc + 3] * h4.w;
        }
        hwp[tid] = (a0 + a1) + (a2 + a3);   // hwp[g*2+hf], linear: conflict-free
        block_sync_lds();
        if (tid < HD) {
            int uu = tid;
            float2 pr = *(const float2*)&hwp[2 * uu];
            float2 pz = *(const float2*)&hwp[2 * (HD + uu)];
            float2 pn_ = *(const float2*)&hwp[2 * (2 * HD + uu)];
            float r = sigm(xr + (pr.x + pr.y));
            float z = sigm(xz + (pz.x + pz.y));
            float nn = tanh_f(xn_ + r * (pn_.x + pn_.y));
            float hnew = (1.f - z) * nn + z * hcur[uu];
            hcur[uu] = hnew;
            y2[(pp * 32 + sq) * 256 + d * HD + uu] = hnew;  // not drained
        }
        block_sync_lds();
        xr = xrn; xz = xzn; xn_ = xnn;
    }
    if (tid < HD) hn2[(d * 32 + sq) * HD + tid] = hcur[tid];
}

// ---------------------------------------------------------------------------
// K4: packet attention + output head (r13/r14 structure).
// ---------------------------------------------------------------------------
__global__ __launch_bounds__(256) void pkt_attn_cls(
    const float* __restrict__ y2, const float* __restrict__ hn2,
    const float* __restrict__ aW, const float* __restrict__ ab,
    const float* __restrict__ cW, const float* __restrict__ cb,
    float* __restrict__ out) {
    const int b = blockIdx.x;
    const int tid = threadIdx.x;
    __shared__ float yl2[32][257];
    __shared__ float hnl[256];
    __shared__ float red[256];
    __shared__ float scl[PD];
    __shared__ float awl[PD];
    __shared__ float ctxl[256];
    __shared__ float ol[HD];
    hnl[tid] = hn2[(((b >> 4) * 32) + 2 * (b & 15) + (tid >> 7)) * HD + (tid & 127)];
    for (int ch = 0; ch < 4; ++ch) {
        __syncthreads();
        for (int idx = tid; idx < 32 * 256; idx += 256) {
            int r = idx >> 8, c = idx & 255;
            yl2[r][c] = y2[((ch * 32 + r) * 32 + b) * 256 + c];
        }
        __syncthreads();
        {
            int r = tid >> 3, seg = tid & 7;
            float acc = 0.f;
            for (int i = 0; i < 32; ++i) {
                int c = seg * 32 + ((i + seg * 4) & 31);
                acc += yl2[r][c] * hnl[c];
            }
            red[tid] = acc;
        }
        __syncthreads();
        if (tid < 32) {
            float s = 0.f;
            #pragma unroll
            for (int k = 0; k < 8; ++k) s += red[tid * 8 + k];
            scl[ch * 32 + tid] = s;
        }
    }
    __syncthreads();
    if (tid < 64) {
        float s0 = scl[tid], s1 = scl[64 + tid];
        float m = fmaxf(s0, s1);
        #pragma unroll
        for (int o = 32; o; o >>= 1) m = fmaxf(m, __shfl_xor(m, o));
        float e0 = __expf(s0 - m), e1 = __expf(s1 - m);
        float ss = e0 + e1;
        #pragma unroll
        for (int o = 32; o; o >>= 1) ss += __shfl_xor(ss, o);
        awl[tid] = e0 / ss; awl[64 + tid] = e1 / ss;
    }
    __syncthreads();
    {
        int c = tid;
        float acc = 0.f;
        for (int p2 = 0; p2 < PD; ++p2) acc += awl[p2] * y2[(p2 * 32 + b) * 256 + c];
        ctxl[c] = acc;
    }
    __syncthreads();
    {
        int h = tid >> 1, hf = tid & 1;
        const float* wr = aW + h * 256 + hf * 128;
        const float* cr = ctxl + hf * 128;
        float acc = 0.f;
        for (int c = 0; c < 128; ++c) acc += cr[c] * wr[c];
        red[hf * 128 + h] = acc;
    }
    __syncthreads();
    if (tid < HD) ol[tid] = red[tid] + red[128 + tid] + ab[tid];
    __syncthreads();
    if (tid < 11) {
        float acc = cb[tid];
        for (int h = 0; h < HD; ++h) acc += ol[h] * cW[tid * HD + h];
        out[b * 11 + tid] = acc;
    }
}

// ---------------------------------------------------------------------------
extern "C" void kernel_launch(void* const* d_in, const int* in_sizes, int n_in,
                              void* d_out, int out_size, void* d_ws, size_t ws_size,
                              hipStream_t stream) {
    const int*   flow = (const int*)d_in[0];
    const float* emb  = (const float*)d_in[1];
    const float* bWih = (const float*)d_in[2];
    const float* bWhh = (const float*)d_in[3];
    const float* baW  = (const float*)d_in[4];
    const float* bab  = (const float*)d_in[5];
    const float* pWih = (const float*)d_in[6];
    const float* pWhh = (const float*)d_in[7];
    const float* paW  = (const float*)d_in[8];
    const float* pab  = (const float*)d_in[9];
    const float* cW   = (const float*)d_in[10];
    const float* cb   = (const float*)d_in[11];
    const float* h0b  = (const float*)d_in[12];
    const float* h0p  = (const float*)d_in[13];
    float* out = (float*)d_out;

    char* ws = (char*)d_ws;
    size_t off = 0;
    unsigned short* y = (unsigned short*)(ws + off); off += (size_t)SD * ND * 256 * 2; // 134 MiB
    float* hn    = (float*)(ws + off); off += (size_t)2 * ND * HD * 4;
    float* pxw   = (float*)(ws + off); off += (size_t)2 * PD * 32 * GD * 4;
    float* y2    = (float*)(ws + off); off += (size_t)PD * 32 * 256 * 4;
    float* hn2   = (float*)(ws + off); off += (size_t)2 * 32 * HD * 4;
    unsigned short* embHi = (unsigned short*)(ws + off); off += (size_t)VD * 64 * 2;   // 8.4 MiB
    float* aWT   = (float*)(ws + off); off += (size_t)256 * 64 * 4;
    float* pWT   = (float*)(ws + off); off += (size_t)2 * 64 * GD * 4;
    if (ws_size < off) return;  // signature: output stays 0 => ws too small

    prep_all<<<(VD * 64 + 255) / 256, 256, 0, stream>>>(emb, embHi, baW, aWT, pWih, pWT);
    byte_gru_mfma<<<256, 512, 0, stream>>>(flow, embHi, bWih, bWhh, h0b, y, hn);
    byte_attn<<<ND, 256, 0, stream>>>(y, hn, aWT, bab, pWT, pxw);
    pkt_gru<<<64, 768, 0, stream>>>(pxw, pWhh, h0p, y2, hn2);
    pkt_attn_cls<<<32, 256, 0, stream>>>(y2, hn2, paW, pab, cW, cb, out);
}

// Round 18
// 453.673 us; speedup vs baseline: 1.3460x; 1.0067x over previous
//
#include <hip/hip_runtime.h>
#include <hip/hip_bf16.h>

// Problem dims (fixed by reference)
#define PD 128   // packets
#define BD 32    // batch
#define SD 64    // bytes per packet (byte-GRU seq len)
#define ED 50    // embedding size
#define HD 128   // hidden (byte and packet)
#define GD 384   // 3*H gates
#define ND 4096  // P*B byte-level batch
#define VD 65536 // vocab
#define LW 128   // LDS row stride in u16 (measured optimum: r7 ladder)

typedef __attribute__((ext_vector_type(8))) short bf16x8;
typedef __attribute__((ext_vector_type(4))) float f32x4;

__device__ __forceinline__ float sigm(float x) { return 1.0f / (1.0f + __expf(-x)); }
__device__ __forceinline__ float tanh_f(float x) { return 1.0f - 2.0f / (__expf(2.0f * x) + 1.0f); }

__device__ __forceinline__ unsigned short f2b(float f) {  // f32 -> bf16 raw, RNE
    union { float f; unsigned u; } a; a.f = f;
    unsigned r = a.u + 0x7FFFu + ((a.u >> 16) & 1u);
    return (unsigned short)(r >> 16);
}
__device__ __forceinline__ float b2f(unsigned short h) {
    union { unsigned u; float f; } a; a.u = ((unsigned)h) << 16; return a.f;
}

union frag_u { bf16x8 v; unsigned short s[8]; };

__device__ __forceinline__ void pin_v(bf16x8& v) { asm volatile("" : "+v"(v)); }

#define MFMA(acc, a, b) acc = __builtin_amdgcn_mfma_f32_16x16x32_bf16(a, b, acc, 0, 0, 0)

// Raw LDS-only barrier: does NOT drain vmcnt (global stores stay in flight).
__device__ __forceinline__ void block_sync_lds() {
    asm volatile("s_waitcnt lgkmcnt(0)" ::: "memory");
    __builtin_amdgcn_sched_barrier(0);
    __builtin_amdgcn_s_barrier();
    __builtin_amdgcn_sched_barrier(0);
}

// ---------------------------------------------------------------------------
// Prep: emb pad+convert; TRANSPOSED attn/packet weights for coalesced reads.
// ---------------------------------------------------------------------------
__global__ void prep_all(const float* __restrict__ emb, unsigned short* __restrict__ embHi,
                         const float* __restrict__ aW, float* __restrict__ aWT,
                         const float* __restrict__ pWih, float* __restrict__ pWT) {
    int idx = blockIdx.x * 256 + threadIdx.x;
    if (idx < VD * 64) {
        int row = idx >> 6, e = idx & 63;
        float v = (e < ED) ? emb[row * ED + e] : 0.f;
        embHi[idx] = f2b(v);
    }
    if (idx < 256 * 64) {
        int c = idx >> 6, e = idx & 63;
        aWT[idx] = (e < ED) ? aW[e * 256 + c] : 0.f;
    }
    if (idx < 2 * 64 * GD) {
        int g = idx % GD, r = idx / GD;   // r = d*64+e
        int d = r >> 6, e = r & 63;
        pWT[idx] = (e < ED) ? pWih[((size_t)(d * GD + g)) * ED + e] : 0.f;
    }
}

// ---------------------------------------------------------------------------
// K1: byte-level bi-GRU via MFMA, split-bf16 precision compensation.
// v18: y stored TRANSPOSED as y[n][s][256] (seq-major) so byte_attn reads one
// contiguous 32KB streak per sequence. Store segments remain 512B contiguous.
// ---------------------------------------------------------------------------
__global__ __attribute__((amdgpu_flat_work_group_size(512, 512), amdgpu_waves_per_eu(2, 2)))
void byte_gru_mfma(
    const int* __restrict__ flow, const unsigned short* __restrict__ embHi,
    const float* __restrict__ Wih, const float* __restrict__ Whh,
    const float* __restrict__ h0b,
    unsigned short* __restrict__ y, float* __restrict__ hn) {
    const int dir   = blockIdx.x >> 7;
    const int chunk = blockIdx.x & 127;
    const int n0    = chunk * 32;
    const int tid   = threadIdx.x;
    const int w     = tid >> 6;
    const int lane  = tid & 63;
    const int col   = lane & 15;
    const int kq    = lane >> 4;
    const int u     = w * 16 + col;

    __shared__ unsigned short HHI[2][32 * LW];
    __shared__ unsigned short HLO[2][32 * LW];
    __shared__ int FLOWT[SD * 32];

    const int yrow = tid >> 4;
    const int yu0  = (tid & 15) * 8;
    const int ysw  = yrow * LW + (yu0 ^ ((yrow & 7) << 3));

    bf16x8 WHh[3][4], WHl[3][4], WXh[3][2], WXl[3][2];
    {
        const float* WhhD = Whh + dir * GD * HD;
        #pragma unroll
        for (int g3 = 0; g3 < 3; ++g3) {
            const float* row = WhhD + (g3 * HD + u) * HD;
            #pragma unroll
            for (int kt = 0; kt < 4; ++kt) {
                const int k0 = kt * 32 + kq * 8;
                frag_u h_, l_;
                #pragma unroll
                for (int b = 0; b < 8; ++b) {
                    float v = row[k0 + b];
                    unsigned short hi = f2b(v);
                    h_.s[b] = hi; l_.s[b] = f2b(v - b2f(hi));
                }
                WHh[g3][kt] = h_.v; WHl[g3][kt] = l_.v;
                pin_v(WHh[g3][kt]); pin_v(WHl[g3][kt]);
            }
        }
        const float* WihD = Wih + dir * GD * ED;
        #pragma unroll
        for (int g3 = 0; g3 < 3; ++g3) {
            const float* row = WihD + (g3 * HD + u) * ED;
            #pragma unroll
            for (int kx = 0; kx < 2; ++kx) {
                const int k0 = kx * 32 + kq * 8;
                frag_u h_, l_;
                #pragma unroll
                for (int b = 0; b < 8; ++b) {
                    const int e = k0 + b;
                    float v = (e < ED) ? row[e] : 0.f;
                    unsigned short hi = f2b(v);
                    h_.s[b] = hi; l_.s[b] = f2b(v - b2f(hi));
                }
                WXh[g3][kx] = h_.v; WXl[g3][kx] = l_.v;
                pin_v(WXh[g3][kx]); pin_v(WXl[g3][kx]);
            }
        }
    }

    float hreg[2][4];
    {
        const float* h0row = h0b + (size_t)((chunk * 2 + dir) * 32) * HD;
        #pragma unroll
        for (int m = 0; m < 2; ++m)
            #pragma unroll
            for (int j = 0; j < 4; ++j)
                hreg[m][j] = h0row[(m * 16 + kq * 4 + j) * HD + u];
        for (int idx = tid; idx < 32 * HD; idx += 512) {
            int seq = idx >> 7, uu = idx & 127;
            float v = h0row[idx];
            unsigned short hi = f2b(v);
            int sw = seq * LW + (uu ^ ((seq & 7) << 3));
            HHI[0][sw] = hi; HLO[0][sw] = f2b(v - b2f(hi));
        }
        for (int j = tid; j < SD * 32; j += 512) {
            int s = j >> 5, seq = j & 31;
            FLOWT[j] = flow[(n0 + seq) * SD + s];
        }
    }
    block_sync_lds();

    bf16x8 xa00, xa01, xa10, xa11;
    {
        const int s0 = dir ? (SD - 1) : 0;
        int i0 = FLOWT[s0 * 32 + col];
        int i1 = FLOWT[s0 * 32 + 16 + col];
        const bf16x8* r0 = (const bf16x8*)(embHi + (size_t)i0 * 64);
        const bf16x8* r1 = (const bf16x8*)(embHi + (size_t)i1 * 64);
        xa00 = r0[kq]; xa01 = r0[4 + kq];
        xa10 = r1[kq]; xa11 = r1[4 + kq];
    }

    int par = 0;
    for (int t = 0; t < SD; ++t) {
        const int s = dir ? (SD - 1 - t) : t;

        if (t > 0) {
            const int sp = dir ? (SD - t) : (t - 1);
            uint4 v = *(const uint4*)&HHI[par][ysw];
            *(uint4*)&y[((size_t)(n0 + yrow) * SD + sp) * 256 + dir * HD + yu0] = v;
        }

        bf16x8 xn00, xn01, xn10, xn11;
        if (t < SD - 1) {
            const int sn = dir ? (SD - 2 - t) : (t + 1);
            int i0 = FLOWT[sn * 32 + col];
            int i1 = FLOWT[sn * 32 + 16 + col];
            const bf16x8* r0 = (const bf16x8*)(embHi + (size_t)i0 * 64);
            const bf16x8* r1 = (const bf16x8*)(embHi + (size_t)i1 * 64);
            xn00 = r0[kq]; xn01 = r0[4 + kq];
            xn10 = r1[kq]; xn11 = r1[4 + kq];
        }

        f32x4 aR[2], aZ[2], aHN[2], aXN[2];
        const f32x4 zero = {0.f, 0.f, 0.f, 0.f};
        #pragma unroll
        for (int m = 0; m < 2; ++m) { aR[m] = zero; aZ[m] = zero; aHN[m] = zero; aXN[m] = zero; }

        const unsigned short* HHIp = HHI[par];
        const unsigned short* HLOp = HLO[par];
        #pragma unroll
        for (int kt = 0; kt < 4; ++kt) {
            const int off = kt * 32 + kq * 8;
            const int sw0 = col * LW + (off ^ ((col & 7) << 3));
            const int sw1 = sw0 + 16 * LW;
            bf16x8 ah0 = *(const bf16x8*)&HHIp[sw0];
            bf16x8 al0 = *(const bf16x8*)&HLOp[sw0];
            bf16x8 ah1 = *(const bf16x8*)&HHIp[sw1];
            bf16x8 al1 = *(const bf16x8*)&HLOp[sw1];
            MFMA(aR[0], ah0, WHh[0][kt]); MFMA(aR[0], al0, WHh[0][kt]); MFMA(aR[0], ah0, WHl[0][kt]);
            MFMA(aZ[0], ah0, WHh[1][kt]); MFMA(aZ[0], al0, WHh[1][kt]); MFMA(aZ[0], ah0, WHl[1][kt]);
            MFMA(aHN[0], ah0, WHh[2][kt]); MFMA(aHN[0], al0, WHh[2][kt]); MFMA(aHN[0], ah0, WHl[2][kt]);
            MFMA(aR[1], ah1, WHh[0][kt]); MFMA(aR[1], al1, WHh[0][kt]); MFMA(aR[1], ah1, WHl[0][kt]);
            MFMA(aZ[1], ah1, WHh[1][kt]); MFMA(aZ[1], al1, WHh[1][kt]); MFMA(aZ[1], ah1, WHl[1][kt]);
            MFMA(aHN[1], ah1, WHh[2][kt]); MFMA(aHN[1], al1, WHh[2][kt]); MFMA(aHN[1], ah1, WHl[2][kt]);
        }
        #pragma unroll
        for (int kx = 0; kx < 2; ++kx) {
            bf16x8 x0 = kx ? xa01 : xa00;
            bf16x8 x1 = kx ? xa11 : xa10;
            MFMA(aR[0], x0, WXh[0][kx]); MFMA(aR[0], x0, WXl[0][kx]);
            MFMA(aZ[0], x0, WXh[1][kx]); MFMA(aZ[0], x0, WXl[1][kx]);
            MFMA(aXN[0], x0, WXh[2][kx]); MFMA(aXN[0], x0, WXl[2][kx]);
            MFMA(aR[1], x1, WXh[0][kx]); MFMA(aR[1], x1, WXl[0][kx]);
            MFMA(aZ[1], x1, WXh[1][kx]); MFMA(aZ[1], x1, WXl[1][kx]);
            MFMA(aXN[1], x1, WXh[2][kx]); MFMA(aXN[1], x1, WXl[2][kx]);
        }

        unsigned short* HHIn = HHI[par ^ 1];
        unsigned short* HLOn = HLO[par ^ 1];
        #pragma unroll
        for (int m = 0; m < 2; ++m)
            #pragma unroll
            for (int j = 0; j < 4; ++j) {
                float r = sigm(aR[m][j]);
                float z = sigm(aZ[m][j]);
                float nn = tanh_f(aXN[m][j] + r * aHN[m][j]);
                float hnew = (1.f - z) * nn + z * hreg[m][j];
                hreg[m][j] = hnew;
                __hip_bfloat16 bh = __float2bfloat16(hnew);
                unsigned short hi = *(unsigned short*)&bh;
                __hip_bfloat16 bl = __float2bfloat16(hnew - b2f(hi));
                const int seq = m * 16 + kq * 4 + j;
                const int sw = seq * LW + (u ^ ((seq & 7) << 3));
                HHIn[sw] = hi;
                HLOn[sw] = *(unsigned short*)&bl;
            }
        block_sync_lds();
        xa00 = xn00; xa01 = xn01; xa10 = xn10; xa11 = xn11;
        par ^= 1;
    }
    {
        const int sl = dir ? 0 : (SD - 1);
        uint4 v = *(const uint4*)&HHI[par][ysw];
        *(uint4*)&y[((size_t)(n0 + yrow) * SD + sl) * 256 + dir * HD + yu0] = v;
    }
    #pragma unroll
    for (int m = 0; m < 2; ++m)
        #pragma unroll
        for (int j = 0; j < 4; ++j) {
            int seq = m * 16 + kq * 4 + j;
            hn[((size_t)dir * ND + n0 + seq) * HD + u] = hreg[m][j];
        }
}

// ---------------------------------------------------------------------------
// K2: byte attention + enc projection + fused pkt-GRU input projection.
// v18: y staging is now one contiguous 32KB streak per block (y[n][s][256]).
// ---------------------------------------------------------------------------
__global__ __launch_bounds__(256) void byte_attn(
    const unsigned short* __restrict__ y, const float* __restrict__ hn,
    const float* __restrict__ aWT, const float* __restrict__ ab,
    const float* __restrict__ pWT, float* __restrict__ pxw) {
    const int n = blockIdx.x;
    const int p = n >> 5, irow = n & 31;
    const int tid = threadIdx.x;
    __shared__ unsigned short yl[SD][256];
    __shared__ float hnl[256];
    __shared__ float red[256];
    __shared__ float red2[256];
    __shared__ float awl[SD];
    __shared__ float ctxl[256];
    __shared__ float encl[64];

    for (int idx = tid; idx < SD * 32; idx += 256) {
        int s = idx >> 5, cc = (idx & 31) * 8;
        *(uint4*)&yl[s][cc] = *(const uint4*)&y[((size_t)n * SD + s) * 256 + cc];
    }
    {   // hn_p reshape quirk: flat idx = irow*256+c over (2,32,128)
        int c = tid;
        int idx = irow * 256 + c;
        int d = idx >> 12, bb = (idx >> 7) & 31, uu = idx & 127;
        hnl[c] = hn[(d * ND + p * 32 + bb) * HD + uu];
    }
    __syncthreads();
    {   // scores: 2-wide, skewed to spread banks
        int s = tid & 63, grp = tid >> 6;
        float acc = 0.f;
        for (int k = 0; k < 32; ++k) {
            int c2 = grp * 32 + ((s + k) & 31);
            unsigned pair = *(const unsigned*)&yl[s][c2 * 2];
            float2 hv = *(const float2*)&hnl[c2 * 2];
            union { unsigned u; float f; } lo, hi;
            lo.u = pair << 16; hi.u = pair & 0xFFFF0000u;
            acc += lo.f * hv.x + hi.f * hv.y;
        }
        red[grp * 64 + s] = acc;
    }
    __syncthreads();
    if (tid < 64) {
        float sc = red[tid] + red[64 + tid] + red[128 + tid] + red[192 + tid];
        float m = sc;
        #pragma unroll
        for (int o = 32; o; o >>= 1) m = fmaxf(m, __shfl_xor(m, o));
        float e = __expf(sc - m);
        float ssum = e;
        #pragma unroll
        for (int o = 32; o; o >>= 1) ssum += __shfl_xor(ssum, o);
        awl[tid] = e / ssum;
    }
    __syncthreads();
    {   // ctx: thread = (column-pair c2, s-half sh); 32 x ds_read_b32 each
        int c2 = tid & 127, sh = tid >> 7;
        float a0 = 0.f, a1 = 0.f;
        const int s0 = sh * 32;
        for (int s = s0; s < s0 + 32; ++s) {
            unsigned pair = *(const unsigned*)&yl[s][c2 * 2];
            union { unsigned u; float f; } lo, hi;
            lo.u = pair << 16; hi.u = pair & 0xFFFF0000u;
            float aw = awl[s];
            a0 += aw * lo.f; a1 += aw * hi.f;
        }
        float* dst = sh ? red2 : red;
        *(float2*)&dst[c2 * 2] = make_float2(a0, a1);
    }
    __syncthreads();
    ctxl[tid] = red[tid] + red2[tid];
    __syncthreads();
    {   // enc[e] partials: coalesced aWT reads
        int e = tid & 63, q = tid >> 6;
        float acc = 0.f;
        for (int c = q * 64; c < q * 64 + 64; ++c) acc += ctxl[c] * aWT[c * 64 + e];
        red[q * 64 + e] = acc;
    }
    __syncthreads();
    if (tid < 64) {
        float v = red[tid] + red[64 + tid] + red[128 + tid] + red[192 + tid];
        encl[tid] = (tid < ED) ? (v + ab[tid]) : 0.f;
    }
    __syncthreads();
    {   // fused pkt_xw: 3 gates per thread, encl loads shared
        int fg0 = tid, fg1 = tid + 256, fg2 = tid + 512;
        int d0 = fg0 >= GD, d1 = fg1 >= GD, d2 = fg2 >= GD;
        int g0 = fg0 - d0 * GD, g1 = fg1 - d1 * GD, g2 = fg2 - d2 * GD;
        const float* wr0 = pWT + (size_t)(d0 * 64) * GD + g0;
        const float* wr1 = pWT + (size_t)(d1 * 64) * GD + g1;
        const float* wr2 = pWT + (size_t)(d2 * 64) * GD + g2;
        float a0 = 0.f, a1 = 0.f, a2 = 0.f;
        #pragma unroll 2
        for (int e = 0; e < ED; ++e) {
            float ev = encl[e];
            size_t o = (size_t)e * GD;
            a0 += ev * wr0[o]; a1 += ev * wr1[o]; a2 += ev * wr2[o];
        }
        pxw[((size_t)(d0 * PD + p) * 32 + irow) * GD + g0] = a0;
        pxw[((size_t)(d1 * PD + p) * 32 + irow) * GD + g1] = a1;
        pxw[((size_t)(d2 * PD + p) * 32 + irow) * GD + g2] = a2;
    }
}

// ---------------------------------------------------------------------------
// K3: packet-level bi-GRU. (r13 split-K structure: best measured.)
// ---------------------------------------------------------------------------
__global__ __launch_bounds__(768, 1) void pkt_gru(
    const float* __restrict__ pxw, const float* __restrict__ Whh,
    const float* __restrict__ h0p,
    float* __restrict__ y2, float* __restrict__ hn2) {
    const int d = blockIdx.x >> 5, sq = blockIdx.x & 31;
    const int tid = threadIdx.x;      // 0..767
    const int g   = tid >> 1;         // gate 0..383
    const int hf  = tid & 1;          // k-half
    __shared__ float hcur[HD];
    __shared__ float hwp[GD * 2];
    float w[64];
    const float* wrow = Whh + (size_t)(d * GD + g) * HD + hf * 64;
    #pragma unroll
    for (int k = 0; k < 64; ++k) w[k] = wrow[k];
    if (tid < HD) hcur[tid] = h0p[(d * 32 + sq) * HD + tid];

    float xr = 0.f, xz = 0.f, xn_ = 0.f;
    if (tid < HD) {
        const int p0 = d ? (PD - 1) : 0;
        const float* xw = pxw + (size_t)((d * PD + p0) * 32 + sq) * GD;
        xr = xw[tid]; xz = xw[HD + tid]; xn_ = xw[2 * HD + tid];
    }
    block_sync_lds();
    for (int t = 0; t < PD; ++t) {
        const int pp = d ? (PD - 1 - t) : t;
        float xrn = 0.f, xzn = 0.f, xnn = 0.f;
        if (t < PD - 1 && tid < HD) {
            const int pn = d ? (PD - 2 - t) : (t + 1);
            const float* xw = pxw + (size_t)((d * PD + pn) * 32 + sq) * GD;
            xrn = xw[tid]; xzn = xw[HD + tid]; xnn = xw[2 * HD + tid];
        }
        float a0 = 0.f, a1 = 0.f, a2 = 0.f, a3 = 0.f;
        const float* hb = &hcur[hf * 64];
        #pragma unroll
        for (int kc = 0; kc < 16; ++kc) {
            float4 h4 = *(const float4*)(hb + kc * 4);
            a0 += w[4 * kc + 0] * h4.x; a1 += w[4 * kc + 1] * h4.y;
            a2 += w[4 * kc + 2] * h4.z; a3 += w[4 * kc + 3] * h4.w;
        }
        hwp[tid] = (a0 + a1) + (a2 + a3);   // hwp[g*2+hf], linear: conflict-free
        block_sync_lds();
        if (tid < HD) {
            int uu = tid;
            float2 pr = *(const float2*)&hwp[2 * uu];
            float2 pz = *(const float2*)&hwp[2 * (HD + uu)];
            float2 pn_ = *(const float2*)&hwp[2 * (2 * HD + uu)];
            float r = sigm(xr + (pr.x + pr.y));
            float z = sigm(xz + (pz.x + pz.y));
            float nn = tanh_f(xn_ + r * (pn_.x + pn_.y));
            float hnew = (1.f - z) * nn + z * hcur[uu];
            hcur[uu] = hnew;
            y2[(pp * 32 + sq) * 256 + d * HD + uu] = hnew;  // not drained
        }
        block_sync_lds();
        xr = xrn; xz = xzn; xn_ = xnn;
    }
    if (tid < HD) hn2[(d * 32 + sq) * HD + tid] = hcur[tid];
}

// ---------------------------------------------------------------------------
// K4: packet attention + output head (r13/r14 structure).
// ---------------------------------------------------------------------------
__global__ __launch_bounds__(256) void pkt_attn_cls(
    const float* __restrict__ y2, const float* __restrict__ hn2,
    const float* __restrict__ aW, const float* __restrict__ ab,
    const float* __restrict__ cW, const float* __restrict__ cb,
    float* __restrict__ out) {
    const int b = blockIdx.x;
    const int tid = threadIdx.x;
    __shared__ float yl2[32][257];
    __shared__ float hnl[256];
    __shared__ float red[256];
    __shared__ float scl[PD];
    __shared__ float awl[PD];
    __shared__ float ctxl[256];
    __shared__ float ol[HD];
    hnl[tid] = hn2[(((b >> 4) * 32) + 2 * (b & 15) + (tid >> 7)) * HD + (tid & 127)];
    for (int ch = 0; ch < 4; ++ch) {
        __syncthreads();
        for (int idx = tid; idx < 32 * 256; idx += 256) {
            int r = idx >> 8, c = idx & 255;
            yl2[r][c] = y2[((ch * 32 + r) * 32 + b) * 256 + c];
        }
        __syncthreads();
        {
            int r = tid >> 3, seg = tid & 7;
            float acc = 0.f;
            for (int i = 0; i < 32; ++i) {
                int c = seg * 32 + ((i + seg * 4) & 31);
                acc += yl2[r][c] * hnl[c];
            }
            red[tid] = acc;
        }
        __syncthreads();
        if (tid < 32) {
            float s = 0.f;
            #pragma unroll
            for (int k = 0; k < 8; ++k) s += red[tid * 8 + k];
            scl[ch * 32 + tid] = s;
        }
    }
    __syncthreads();
    if (tid < 64) {
        float s0 = scl[tid], s1 = scl[64 + tid];
        float m = fmaxf(s0, s1);
        #pragma unroll
        for (int o = 32; o; o >>= 1) m = fmaxf(m, __shfl_xor(m, o));
        float e0 = __expf(s0 - m), e1 = __expf(s1 - m);
        float ss = e0 + e1;
        #pragma unroll
        for (int o = 32; o; o >>= 1) ss += __shfl_xor(ss, o);
        awl[tid] = e0 / ss; awl[64 + tid] = e1 / ss;
    }
    __syncthreads();
    {
        int c = tid;
        float acc = 0.f;
        for (int p2 = 0; p2 < PD; ++p2) acc += awl[p2] * y2[(p2 * 32 + b) * 256 + c];
        ctxl[c] = acc;
    }
    __syncthreads();
    {
        int h = tid >> 1, hf = tid & 1;
        const float* wr = aW + h * 256 + hf * 128;
        const float* cr = ctxl + hf * 128;
        float acc = 0.f;
        for (int c = 0; c < 128; ++c) acc += cr[c] * wr[c];
        red[hf * 128 + h] = acc;
    }
    __syncthreads();
    if (tid < HD) ol[tid] = red[tid] + red[128 + tid] + ab[tid];
    __syncthreads();
    if (tid < 11) {
        float acc = cb[tid];
        for (int h = 0; h < HD; ++h) acc += ol[h] * cW[tid * HD + h];
        out[b * 11 + tid] = acc;
    }
}

// ---------------------------------------------------------------------------
extern "C" void kernel_launch(void* const* d_in, const int* in_sizes, int n_in,
                              void* d_out, int out_size, void* d_ws, size_t ws_size,
                              hipStream_t stream) {
    const int*   flow = (const int*)d_in[0];
    const float* emb  = (const float*)d_in[1];
    const float* bWih = (const float*)d_in[2];
    const float* bWhh = (const float*)d_in[3];
    const float* baW  = (const float*)d_in[4];
    const float* bab  = (const float*)d_in[5];
    const float* pWih = (const float*)d_in[6];
    const float* pWhh = (const float*)d_in[7];
    const float* paW  = (const float*)d_in[8];
    const float* pab  = (const float*)d_in[9];
    const float* cW   = (const float*)d_in[10];
    const float* cb   = (const float*)d_in[11];
    const float* h0b  = (const float*)d_in[12];
    const float* h0p  = (const float*)d_in[13];
    float* out = (float*)d_out;

    char* ws = (char*)d_ws;
    size_t off = 0;
    unsigned short* y = (unsigned short*)(ws + off); off += (size_t)SD * ND * 256 * 2; // 134 MiB
    float* hn    = (float*)(ws + off); off += (size_t)2 * ND * HD * 4;
    float* pxw   = (float*)(ws + off); off += (size_t)2 * PD * 32 * GD * 4;
    float* y2    = (float*)(ws + off); off += (size_t)PD * 32 * 256 * 4;
    float* hn2   = (float*)(ws + off); off += (size_t)2 * 32 * HD * 4;
    unsigned short* embHi = (unsigned short*)(ws + off); off += (size_t)VD * 64 * 2;   // 8.4 MiB
    float* aWT   = (float*)(ws + off); off += (size_t)256 * 64 * 4;
    float* pWT   = (float*)(ws + off); off += (size_t)2 * 64 * GD * 4;
    if (ws_size < off) return;  // signature: output stays 0 => ws too small

    prep_all<<<(VD * 64 + 255) / 256, 256, 0, stream>>>(emb, embHi, baW, aWT, pWih, pWT);
    byte_gru_mfma<<<256, 512, 0, stream>>>(flow, embHi, bWih, bWhh, h0b, y, hn);
    byte_attn<<<ND, 256, 0, stream>>>(y, hn, aWT, bab, pWT, pxw);
    pkt_gru<<<64, 768, 0, stream>>>(pxw, pWhh, h0p, y2, hn2);
    pkt_attn_cls<<<32, 256, 0, stream>>>(y2, hn2, paW, pab, cW, cb, out);
}